// Round 5
// baseline (468.073 us; speedup 1.0000x reference)
//
#include <hip/hip_runtime.h>

// LGCN_REL_EMB — atomic-free restructure (round 5).
//   Sort triples by key b = fr*16 + rel (counting sort, 800K buckets).
//   k_h   : wave per f, h[f,:] = relu(b1 + sum w*w1[r,to,:])      (no atomics)
//   k_h2  : wave per f, h2[f, r*32+e] = (1/len) sum h[to,e]       (no atomics)
//   k_gemm: out = h2 (N x 512) @ w2 (512 x 50) + b2               (no atomics)
// Lessons kept: round-2 — scattered multi-atomics cause per-line HBM RMW;
// round-4 — even coalesced row-atomics floor at ~84us (12.5M lane-ops).
// NOTE: packs `to` in 16 bits — requires N <= 65536 (N=50000 here).

#define RP 16
#define EDIM 32
#define CDIM 50
#define KDIM (RP * EDIM)   // 512

// ---------- histogram over buckets b = f*RP + r
__global__ void k_hist(const int* __restrict__ fr, const int* __restrict__ rel,
                       int* __restrict__ bucket, int T) {
    int t = blockIdx.x * blockDim.x + threadIdx.x;
    if (t < T) atomicAdd(&bucket[fr[t] * RP + rel[t]], 1);
}

// ---------- 3-kernel exclusive scan over n=NB elements (1024 elems/block)
__global__ void k_scan1(const int* __restrict__ A, int* __restrict__ partials, int n) {
    __shared__ int lds[256];
    int tid = threadIdx.x;
    int base = blockIdx.x * 1024 + tid * 4;
    int s = 0;
    #pragma unroll
    for (int q = 0; q < 4; ++q) { int i = base + q; if (i < n) s += A[i]; }
    lds[tid] = s; __syncthreads();
    for (int off = 128; off > 0; off >>= 1) {
        if (tid < off) lds[tid] += lds[tid + off];
        __syncthreads();
    }
    if (tid == 0) partials[blockIdx.x] = lds[0];
}

__global__ void k_scan2(int* __restrict__ partials, int nblk) {
    __shared__ int lds[1024];
    __shared__ int carry;
    int tid = threadIdx.x;
    if (tid == 0) carry = 0;
    __syncthreads();
    for (int base = 0; base < nblk; base += 1024) {
        int i = base + tid;
        int v = (i < nblk) ? partials[i] : 0;
        lds[tid] = v; __syncthreads();
        for (int off = 1; off < 1024; off <<= 1) {
            int x = (tid >= off) ? lds[tid - off] : 0;
            __syncthreads();
            lds[tid] += x;
            __syncthreads();
        }
        int incl = lds[tid];
        int mycarry = carry;
        if (i < nblk) partials[i] = incl - v + mycarry;
        __syncthreads();
        if (tid == 0) carry = mycarry + lds[1023];
        __syncthreads();
    }
}

// row_ptr[i] = exscan; cursor gets same value (cursor may alias A, in-place safe:
// each element is read then written by the same thread only).
__global__ void k_scan3(const int* __restrict__ A, const int* __restrict__ partials,
                        int* __restrict__ row_ptr, int* __restrict__ cursor, int n) {
    __shared__ int lds[256];
    int tid = threadIdx.x;
    int base = blockIdx.x * 1024 + tid * 4;
    int v[4]; int s = 0;
    #pragma unroll
    for (int q = 0; q < 4; ++q) { int i = base + q; v[q] = (i < n) ? A[i] : 0; s += v[q]; }
    lds[tid] = s; __syncthreads();
    for (int off = 1; off < 256; off <<= 1) {
        int x = (tid >= off) ? lds[tid - off] : 0;
        __syncthreads();
        lds[tid] += x;
        __syncthreads();
    }
    int p = lds[tid] - s + partials[blockIdx.x];
    #pragma unroll
    for (int q = 0; q < 4; ++q) {
        int i = base + q;
        if (i < n) {
            row_ptr[i] = p;
            cursor[i] = p;
            if (i == n - 1) row_ptr[n] = p + v[q];
            p += v[q];
        }
    }
}

// ---------- scatter payload (rel<<16 | to) into sorted order
__global__ void k_scatter(const int* __restrict__ fr, const int* __restrict__ to,
                          const int* __restrict__ rel, int* __restrict__ cursor,
                          int* __restrict__ packed, int T) {
    int t = blockIdx.x * blockDim.x + threadIdx.x;
    if (t < T) {
        int b = fr[t] * RP + rel[t];
        int pos = atomicAdd(&cursor[b], 1);
        packed[pos] = (rel[t] << 16) | to[t];
    }
}

// ---------- h[f,:] = relu(b1 + sum_t (1/len(f,r_t)) * w1[r_t, to_t, :])
// wave per f; even/odd slots split across half-waves; combine via shfl_xor(32).
__global__ __launch_bounds__(256)
void k_h(const int* __restrict__ row_ptr, const int* __restrict__ packed,
         const float* __restrict__ w1, const float* __restrict__ b1,
         float* __restrict__ h, int N) {
    int f = blockIdx.x * 4 + (threadIdx.x >> 6);
    if (f >= N) return;
    int lane = threadIdx.x & 63;
    int half = lane >> 5;
    int e = lane & 31;
    int s    = row_ptr[f * RP];
    int eend = row_ptr[f * RP + RP];
    float acc = 0.f;
    for (int j = s + half; j < eend; j += 2) {
        int p = packed[j];
        int r = p >> 16, o = p & 0xFFFF;
        int rb = f * RP + r;
        float w = 1.0f / (float)(row_ptr[rb + 1] - row_ptr[rb]);
        acc += w * w1[((size_t)r * N + o) * EDIM + e];
    }
    acc += __shfl_xor(acc, 32, 64);
    if (lane < 32) h[(size_t)f * EDIM + e] = fmaxf(acc + b1[e], 0.f);
}

// ---------- h2[f - f0, r*32+e] = (1/len) * sum_run h[to, e]
// wave per f; half-waves take even/odd r; empty runs write 0 (no memset needed).
__global__ __launch_bounds__(256)
void k_h2(const int* __restrict__ row_ptr, const int* __restrict__ packed,
          const float* __restrict__ h, float* __restrict__ h2,
          int f0, int fend) {
    int f = f0 + blockIdx.x * 4 + (threadIdx.x >> 6);
    if (f >= fend) return;
    int lane = threadIdx.x & 63;
    int half = lane >> 5;
    int e = lane & 31;
    float* dst = h2 + (size_t)(f - f0) * KDIM;
    for (int k8 = 0; k8 < 8; ++k8) {
        int r = k8 * 2 + half;
        int rb = f * RP + r;
        int s0 = row_ptr[rb], e0 = row_ptr[rb + 1];
        float acc = 0.f;
        for (int j = s0; j < e0; ++j) {
            int o = packed[j] & 0xFFFF;
            acc += h[(size_t)o * EDIM + e];
        }
        float w = (e0 > s0) ? 1.0f / (float)(e0 - s0) : 0.0f;
        dst[r * EDIM + e] = w * acc;
    }
}

// ---------- out[f, c] = b2[c] + sum_k h2[f, k] * w2[k, c]
// block = 64 rows; wave = 16 rows; lane = c (50 active). w2 chunk in registers.
__global__ __launch_bounds__(256)
void k_gemm(const float* __restrict__ h2, const float* __restrict__ w2,
            const float* __restrict__ b2, float* __restrict__ out,
            int f0, int fend) {
    int wv = threadIdx.x >> 6;
    int lane = threadIdx.x & 63;
    int rowbase = f0 + blockIdx.x * 64 + wv * 16;
    int nrows = fend - rowbase;
    if (nrows <= 0) return;
    if (nrows > 16) nrows = 16;
    bool cok = lane < CDIM;
    int c = cok ? lane : CDIM - 1;
    float acc[16];
    #pragma unroll
    for (int i = 0; i < 16; ++i) acc[i] = 0.f;
    for (int kb = 0; kb < KDIM / 32; ++kb) {
        float wreg[32];
        #pragma unroll
        for (int kk = 0; kk < 32; ++kk) wreg[kk] = w2[(kb * 32 + kk) * CDIM + c];
        #pragma unroll
        for (int r16 = 0; r16 < 16; ++r16) {     // static bound; guard inside (reg-indexed acc)
            if (r16 < nrows) {
                const float4* hp = (const float4*)(h2 + (size_t)(rowbase - f0 + r16) * KDIM + kb * 32);
                #pragma unroll
                for (int q = 0; q < 8; ++q) {
                    float4 hv = hp[q];
                    acc[r16] = fmaf(hv.x, wreg[4 * q + 0], acc[r16]);
                    acc[r16] = fmaf(hv.y, wreg[4 * q + 1], acc[r16]);
                    acc[r16] = fmaf(hv.z, wreg[4 * q + 2], acc[r16]);
                    acc[r16] = fmaf(hv.w, wreg[4 * q + 3], acc[r16]);
                }
            }
        }
    }
    if (cok) {
        float bb = b2[c];
        #pragma unroll
        for (int r16 = 0; r16 < 16; ++r16)
            if (r16 < nrows)
                out[(size_t)(rowbase + r16) * CDIM + c] = acc[r16] + bb;
    }
}

extern "C" void kernel_launch(void* const* d_in, const int* in_sizes, int n_in,
                              void* d_out, int out_size, void* d_ws, size_t ws_size,
                              hipStream_t stream) {
    const int*   fr  = (const int*)d_in[0];
    const int*   to  = (const int*)d_in[1];
    const int*   rel = (const int*)d_in[2];
    const float* w1  = (const float*)d_in[3];
    const float* w2  = (const float*)d_in[4];
    const float* b1  = (const float*)d_in[5];
    const float* b2  = (const float*)d_in[6];
    float* out = (float*)d_out;

    const int T  = in_sizes[0];
    const int N  = in_sizes[3] / (RP * EDIM);
    const int NB = N * RP;

    // ---- workspace carve (256B aligned)
    char* p = (char*)d_ws;
    auto alloc = [&](size_t bytes) { char* q = p; p += (bytes + 255) & ~(size_t)255; return q; };
    int* bucket   = (int*)alloc((size_t)NB * 4);          // hist -> cursor (in-place)
    int* row_ptr  = (int*)alloc(((size_t)NB + 1) * 4);
    int* partials = (int*)alloc(4096);                    // up to 1024 scan blocks
    int* packed   = (int*)alloc((size_t)T * 4);
    float* h      = (float*)alloc((size_t)N * EDIM * 4);
    // h2 takes the rest; chunk over f if it doesn't all fit
    size_t used = (size_t)(p - (char*)d_ws);
    size_t room = (ws_size > used) ? ws_size - used : 0;
    size_t rows_fit = room / ((size_t)KDIM * 4);
    int chunk = (rows_fit >= (size_t)N) ? N : (int)rows_fit;
    chunk = (chunk / 64) * 64;
    if (chunk < 64) chunk = 64;   // last-resort floor
    float* h2 = (float*)p;

    const int B = 256;
    hipMemsetAsync(bucket, 0, (size_t)NB * 4, stream);
    k_hist<<<(T + B - 1) / B, B, 0, stream>>>(fr, rel, bucket, T);

    const int nblk = (NB + 1023) / 1024;
    k_scan1<<<nblk, 256, 0, stream>>>(bucket, partials, NB);
    k_scan2<<<1, 1024, 0, stream>>>(partials, nblk);
    k_scan3<<<nblk, 256, 0, stream>>>(bucket, partials, row_ptr, bucket, NB);

    k_scatter<<<(T + B - 1) / B, B, 0, stream>>>(fr, to, rel, bucket, packed, T);

    k_h<<<(N + 3) / 4, 256, 0, stream>>>(row_ptr, packed, w1, b1, h, N);

    for (int f0 = 0; f0 < N; f0 += chunk) {
        int fend = (f0 + chunk < N) ? f0 + chunk : N;
        int nf = fend - f0;
        k_h2<<<(nf + 3) / 4, 256, 0, stream>>>(row_ptr, packed, h, h2, f0, fend);
        k_gemm<<<(nf + 63) / 64, 256, 0, stream>>>(h2, w2, b2, out, f0, fend);
    }
}

// Round 6
// 230.537 us; speedup vs baseline: 2.0304x; 2.0304x over previous
//
#include <hip/hip_runtime.h>

// LGCN_REL_EMB — atomic-free, fused output (round 6).
//   Counting sort by bucket b = fr*16 + rel (row_ptr over 800K buckets).
//   k_h   : wave per f: h[f,:] = relu(b1 + sum_t w*w1[r_t,to_t,:])   (no atomics)
//   k_out : wave per 8 f's, lanes=c: out[f,c] = b2[c] +
//             sum_r (1/len_{f,r}) sum_{to in run} dot(h[to,:], w2[r,:,c])
//           w2 column in regs per lane, reloaded once per (r, 8 nodes);
//           plain coalesced row stores (no atomics, no out-init, no h2).
// Lessons: r2 — scattered multi-atomics => per-line HBM RMW; r4 — coalesced
// atomics floor ~84us; r5 — broadcast-load GEMM + materialized h2 (204MB) is
// far worse than fusing the 512x50 matvec into the gather.
// NOTE: packs `to` in 16 bits — requires N <= 65536 (N=50000 here).

#define RP 16
#define EDIM 32
#define CDIM 50

// ---------- histogram over buckets b = f*RP + r
__global__ void k_hist(const int* __restrict__ fr, const int* __restrict__ rel,
                       int* __restrict__ bucket, int T) {
    int t = blockIdx.x * blockDim.x + threadIdx.x;
    if (t < T) atomicAdd(&bucket[fr[t] * RP + rel[t]], 1);
}

// ---------- 3-kernel exclusive scan over n elements (1024 elems/block)
__global__ void k_scan1(const int* __restrict__ A, int* __restrict__ partials, int n) {
    __shared__ int lds[256];
    int tid = threadIdx.x;
    int base = blockIdx.x * 1024 + tid * 4;
    int s = 0;
    #pragma unroll
    for (int q = 0; q < 4; ++q) { int i = base + q; if (i < n) s += A[i]; }
    lds[tid] = s; __syncthreads();
    for (int off = 128; off > 0; off >>= 1) {
        if (tid < off) lds[tid] += lds[tid + off];
        __syncthreads();
    }
    if (tid == 0) partials[blockIdx.x] = lds[0];
}

__global__ void k_scan2(int* __restrict__ partials, int nblk) {
    __shared__ int lds[1024];
    __shared__ int carry;
    int tid = threadIdx.x;
    if (tid == 0) carry = 0;
    __syncthreads();
    for (int base = 0; base < nblk; base += 1024) {
        int i = base + tid;
        int v = (i < nblk) ? partials[i] : 0;
        lds[tid] = v; __syncthreads();
        for (int off = 1; off < 1024; off <<= 1) {
            int x = (tid >= off) ? lds[tid - off] : 0;
            __syncthreads();
            lds[tid] += x;
            __syncthreads();
        }
        int incl = lds[tid];
        int mycarry = carry;
        if (i < nblk) partials[i] = incl - v + mycarry;
        __syncthreads();
        if (tid == 0) carry = mycarry + lds[1023];
        __syncthreads();
    }
}

__global__ void k_scan3(const int* __restrict__ A, const int* __restrict__ partials,
                        int* __restrict__ row_ptr, int* __restrict__ cursor, int n) {
    __shared__ int lds[256];
    int tid = threadIdx.x;
    int base = blockIdx.x * 1024 + tid * 4;
    int v[4]; int s = 0;
    #pragma unroll
    for (int q = 0; q < 4; ++q) { int i = base + q; v[q] = (i < n) ? A[i] : 0; s += v[q]; }
    lds[tid] = s; __syncthreads();
    for (int off = 1; off < 256; off <<= 1) {
        int x = (tid >= off) ? lds[tid - off] : 0;
        __syncthreads();
        lds[tid] += x;
        __syncthreads();
    }
    int p = lds[tid] - s + partials[blockIdx.x];
    #pragma unroll
    for (int q = 0; q < 4; ++q) {
        int i = base + q;
        if (i < n) {
            row_ptr[i] = p;
            cursor[i] = p;
            if (i == n - 1) row_ptr[n] = p + v[q];
            p += v[q];
        }
    }
}

// ---------- scatter payload (rel<<16 | to) into sorted order
__global__ void k_scatter(const int* __restrict__ fr, const int* __restrict__ to,
                          const int* __restrict__ rel, int* __restrict__ cursor,
                          int* __restrict__ packed, int T) {
    int t = blockIdx.x * blockDim.x + threadIdx.x;
    if (t < T) {
        int b = fr[t] * RP + rel[t];
        int pos = atomicAdd(&cursor[b], 1);
        packed[pos] = (rel[t] << 16) | to[t];
    }
}

// ---------- h[f,:] = relu(b1 + sum_t (1/len(f,r_t)) * w1[r_t, to_t, :])
// wave per f; even/odd slots across half-waves; combine via shfl_xor(32).
__global__ __launch_bounds__(256)
void k_h(const int* __restrict__ row_ptr, const int* __restrict__ packed,
         const float* __restrict__ w1, const float* __restrict__ b1,
         float* __restrict__ h, int N) {
    int f = blockIdx.x * 4 + (threadIdx.x >> 6);
    if (f >= N) return;
    int lane = threadIdx.x & 63;
    int half = lane >> 5;
    int e = lane & 31;
    int s    = row_ptr[f * RP];
    int eend = row_ptr[f * RP + RP];
    float acc = 0.f;
    for (int j = s + half; j < eend; j += 2) {
        int p = packed[j];
        int r = p >> 16, o = p & 0xFFFF;
        int rb = f * RP + r;
        float w = 1.0f / (float)(row_ptr[rb + 1] - row_ptr[rb]);
        acc += w * w1[((size_t)r * N + o) * EDIM + e];
    }
    acc += __shfl_xor(acc, 32, 64);
    if (lane < 32) h[(size_t)f * EDIM + e] = fmaxf(acc + b1[e], 0.f);
}

// ---------- fused second hop + classifier, no atomics
// wave per 8 f's, lanes = c. For each r: w2 column (32 floats) in regs,
// walk the 8 (f,r) runs: per triple 8 broadcast float4 h-loads + 32 FMA.
#define GF 8
__global__ __launch_bounds__(256)
void k_out(const int* __restrict__ row_ptr, const int* __restrict__ packed,
           const float* __restrict__ h, const float* __restrict__ w2,
           const float* __restrict__ b2, float* __restrict__ out, int N) {
    int fbase = (blockIdx.x * 4 + (threadIdx.x >> 6)) * GF;
    if (fbase >= N) return;
    int lane = threadIdx.x & 63;
    int c = (lane < CDIM) ? lane : CDIM - 1;

    float acc[GF];
    #pragma unroll
    for (int g = 0; g < GF; ++g) acc[g] = 0.f;

    for (int r = 0; r < RP; ++r) {
        float w2c[EDIM];
        const float* wp = w2 + r * (EDIM * CDIM) + c;
        #pragma unroll
        for (int e = 0; e < EDIM; ++e) w2c[e] = wp[e * CDIM];

        #pragma unroll
        for (int g = 0; g < GF; ++g) {
            int f = fbase + g;
            if (f < N) {
                int rb = f * RP + r;
                int s0 = row_ptr[rb], e0 = row_ptr[rb + 1];
                if (s0 < e0) {
                    float racc = 0.f;
                    for (int j = s0; j < e0; ++j) {
                        int o = packed[j] & 0xFFFF;
                        const float4* __restrict__ hp =
                            reinterpret_cast<const float4*>(h + (size_t)o * EDIM);
                        float dot = 0.f;
                        #pragma unroll
                        for (int q = 0; q < 8; ++q) {
                            float4 hv = hp[q];
                            dot = fmaf(hv.x, w2c[4 * q + 0], dot);
                            dot = fmaf(hv.y, w2c[4 * q + 1], dot);
                            dot = fmaf(hv.z, w2c[4 * q + 2], dot);
                            dot = fmaf(hv.w, w2c[4 * q + 3], dot);
                        }
                        racc += dot;
                    }
                    acc[g] += racc * (1.0f / (float)(e0 - s0));
                }
            }
        }
    }

    if (lane < CDIM) {
        float bb = b2[c];
        #pragma unroll
        for (int g = 0; g < GF; ++g) {
            int f = fbase + g;
            if (f < N) out[(size_t)f * CDIM + c] = acc[g] + bb;
        }
    }
}

extern "C" void kernel_launch(void* const* d_in, const int* in_sizes, int n_in,
                              void* d_out, int out_size, void* d_ws, size_t ws_size,
                              hipStream_t stream) {
    const int*   fr  = (const int*)d_in[0];
    const int*   to  = (const int*)d_in[1];
    const int*   rel = (const int*)d_in[2];
    const float* w1  = (const float*)d_in[3];
    const float* w2  = (const float*)d_in[4];
    const float* b1  = (const float*)d_in[5];
    const float* b2  = (const float*)d_in[6];
    float* out = (float*)d_out;

    const int T  = in_sizes[0];
    const int N  = in_sizes[3] / (RP * EDIM);
    const int NB = N * RP;

    // ---- workspace carve (256B aligned)
    char* p = (char*)d_ws;
    auto alloc = [&](size_t bytes) { char* q = p; p += (bytes + 255) & ~(size_t)255; return q; };
    int*   bucket   = (int*)alloc((size_t)NB * 4);        // hist -> cursor (in-place)
    int*   row_ptr  = (int*)alloc(((size_t)NB + 1) * 4);
    int*   partials = (int*)alloc(4096);
    int*   packed   = (int*)alloc((size_t)T * 4);
    float* h        = (float*)alloc((size_t)N * EDIM * 4);

    const int B = 256;
    hipMemsetAsync(bucket, 0, (size_t)NB * 4, stream);
    k_hist<<<(T + B - 1) / B, B, 0, stream>>>(fr, rel, bucket, T);

    const int nblk = (NB + 1023) / 1024;
    k_scan1<<<nblk, 256, 0, stream>>>(bucket, partials, NB);
    k_scan2<<<1, 1024, 0, stream>>>(partials, nblk);
    k_scan3<<<nblk, 256, 0, stream>>>(bucket, partials, row_ptr, bucket, NB);

    k_scatter<<<(T + B - 1) / B, B, 0, stream>>>(fr, to, rel, bucket, packed, T);

    k_h<<<(N + 3) / 4, 256, 0, stream>>>(row_ptr, packed, w1, b1, h, N);

    const int fpb = 4 * GF;   // f's per block
    k_out<<<(N + fpb - 1) / fpb, 256, 0, stream>>>(row_ptr, packed, h, w2, b2, out, N);
}

// Round 7
// 207.420 us; speedup vs baseline: 2.2566x; 1.1114x over previous
//
#include <hip/hip_runtime.h>

// LGCN_REL_EMB — atomic-free, fused output (round 7).
//   Counting sort by bucket b = fr*16 + rel (row_ptr over 800K buckets).
//   k_h   : wave per f: h[f,:] = relu(b1 + sum_t w*w1[r_t,to_t,:])   (no atomics)
//   k_out : block = 16 f's, 4 waves; wave w owns relations r in [4w,4w+4).
//           Lane = c holds w2[r] column in regs (reloaded once per r per wave,
//           32 loads amortized over ~5 triples); per-lane reg acc[16] (static
//           unroll); cross-wave combine via small LDS; coalesced row stores.
// Lessons: r2 — scattered multi-atomics => per-line HBM RMW; r4 — coalesced
// atomics floor ~84us (TCC lane-op throughput); r5 — broadcast-load GEMM +
// materialized h2 is worse than fusing; r6 — wave-per-8f starves occupancy
// (35%) and churns w2 (512 loads/wave).
// NOTE: packs `to` in 16 bits — requires N <= 65536 (N=50000 here).

#define RP 16
#define EDIM 32
#define CDIM 50
#define BF 16      // f's per block in k_out
#define CPAD 52    // LDS c-pad

// ---------- histogram over buckets b = f*RP + r
__global__ void k_hist(const int* __restrict__ fr, const int* __restrict__ rel,
                       int* __restrict__ bucket, int T) {
    int t = blockIdx.x * blockDim.x + threadIdx.x;
    if (t < T) atomicAdd(&bucket[fr[t] * RP + rel[t]], 1);
}

// ---------- 3-kernel exclusive scan over n elements (1024 elems/block)
__global__ void k_scan1(const int* __restrict__ A, int* __restrict__ partials, int n) {
    __shared__ int lds[256];
    int tid = threadIdx.x;
    int base = blockIdx.x * 1024 + tid * 4;
    int s = 0;
    #pragma unroll
    for (int q = 0; q < 4; ++q) { int i = base + q; if (i < n) s += A[i]; }
    lds[tid] = s; __syncthreads();
    for (int off = 128; off > 0; off >>= 1) {
        if (tid < off) lds[tid] += lds[tid + off];
        __syncthreads();
    }
    if (tid == 0) partials[blockIdx.x] = lds[0];
}

__global__ void k_scan2(int* __restrict__ partials, int nblk) {
    __shared__ int lds[1024];
    __shared__ int carry;
    int tid = threadIdx.x;
    if (tid == 0) carry = 0;
    __syncthreads();
    for (int base = 0; base < nblk; base += 1024) {
        int i = base + tid;
        int v = (i < nblk) ? partials[i] : 0;
        lds[tid] = v; __syncthreads();
        for (int off = 1; off < 1024; off <<= 1) {
            int x = (tid >= off) ? lds[tid - off] : 0;
            __syncthreads();
            lds[tid] += x;
            __syncthreads();
        }
        int incl = lds[tid];
        int mycarry = carry;
        if (i < nblk) partials[i] = incl - v + mycarry;
        __syncthreads();
        if (tid == 0) carry = mycarry + lds[1023];
        __syncthreads();
    }
}

__global__ void k_scan3(const int* __restrict__ A, const int* __restrict__ partials,
                        int* __restrict__ row_ptr, int* __restrict__ cursor, int n) {
    __shared__ int lds[256];
    int tid = threadIdx.x;
    int base = blockIdx.x * 1024 + tid * 4;
    int v[4]; int s = 0;
    #pragma unroll
    for (int q = 0; q < 4; ++q) { int i = base + q; v[q] = (i < n) ? A[i] : 0; s += v[q]; }
    lds[tid] = s; __syncthreads();
    for (int off = 1; off < 256; off <<= 1) {
        int x = (tid >= off) ? lds[tid - off] : 0;
        __syncthreads();
        lds[tid] += x;
        __syncthreads();
    }
    int p = lds[tid] - s + partials[blockIdx.x];
    #pragma unroll
    for (int q = 0; q < 4; ++q) {
        int i = base + q;
        if (i < n) {
            row_ptr[i] = p;
            cursor[i] = p;
            if (i == n - 1) row_ptr[n] = p + v[q];
            p += v[q];
        }
    }
}

// ---------- scatter payload (rel<<16 | to) into sorted order
__global__ void k_scatter(const int* __restrict__ fr, const int* __restrict__ to,
                          const int* __restrict__ rel, int* __restrict__ cursor,
                          int* __restrict__ packed, int T) {
    int t = blockIdx.x * blockDim.x + threadIdx.x;
    if (t < T) {
        int b = fr[t] * RP + rel[t];
        int pos = atomicAdd(&cursor[b], 1);
        packed[pos] = (rel[t] << 16) | to[t];
    }
}

// ---------- h[f,:] = relu(b1 + sum_t (1/len(f,r_t)) * w1[r_t, to_t, :])
__global__ __launch_bounds__(256)
void k_h(const int* __restrict__ row_ptr, const int* __restrict__ packed,
         const float* __restrict__ w1, const float* __restrict__ b1,
         float* __restrict__ h, int N) {
    int f = blockIdx.x * 4 + (threadIdx.x >> 6);
    if (f >= N) return;
    int lane = threadIdx.x & 63;
    int half = lane >> 5;
    int e = lane & 31;
    int s    = row_ptr[f * RP];
    int eend = row_ptr[f * RP + RP];
    float acc = 0.f;
    for (int j = s + half; j < eend; j += 2) {
        int p = packed[j];
        int r = p >> 16, o = p & 0xFFFF;
        int rb = f * RP + r;
        float w = 1.0f / (float)(row_ptr[rb + 1] - row_ptr[rb]);
        acc += w * w1[((size_t)r * N + o) * EDIM + e];
    }
    acc += __shfl_xor(acc, 32, 64);
    if (lane < 32) h[(size_t)f * EDIM + e] = fmaxf(acc + b1[e], 0.f);
}

// ---------- fused second hop + classifier, no atomics
__global__ __launch_bounds__(256)
void k_out(const int* __restrict__ row_ptr, const int* __restrict__ packed,
           const float* __restrict__ h, const float* __restrict__ w2,
           const float* __restrict__ b2, float* __restrict__ out, int N) {
    __shared__ float acc4[4][BF][CPAD];
    const int tid  = threadIdx.x;
    const int wv   = tid >> 6;           // 0..3  -> relations [4wv, 4wv+4)
    const int lane = tid & 63;
    const int c    = (lane < CDIM) ? lane : CDIM - 1;
    const int fbase = blockIdx.x * BF;

    float acc[BF];
    #pragma unroll
    for (int g = 0; g < BF; ++g) acc[g] = 0.f;

    for (int rr = 0; rr < 4; ++rr) {
        const int r = wv * 4 + rr;
        float w2c[EDIM];
        {
            const float* wp = w2 + r * (EDIM * CDIM) + c;
            #pragma unroll
            for (int e = 0; e < EDIM; ++e) w2c[e] = wp[e * CDIM];
        }
        #pragma unroll
        for (int g = 0; g < BF; ++g) {
            int f = fbase + g;
            if (f < N) {
                int rb = f * RP + r;
                int s0 = row_ptr[rb], e0 = row_ptr[rb + 1];
                if (s0 < e0) {
                    float racc = 0.f;
                    for (int j = s0; j < e0; ++j) {
                        int o = packed[j] & 0xFFFF;
                        const float4* __restrict__ hp =
                            reinterpret_cast<const float4*>(h + (size_t)o * EDIM);
                        float dot = 0.f;
                        #pragma unroll
                        for (int q = 0; q < 8; ++q) {
                            float4 hv = hp[q];
                            dot = fmaf(hv.x, w2c[4 * q + 0], dot);
                            dot = fmaf(hv.y, w2c[4 * q + 1], dot);
                            dot = fmaf(hv.z, w2c[4 * q + 2], dot);
                            dot = fmaf(hv.w, w2c[4 * q + 3], dot);
                        }
                        racc += dot;
                    }
                    acc[g] += racc * (1.0f / (float)(e0 - s0));
                }
            }
        }
    }

    if (lane < CDIM) {
        #pragma unroll
        for (int g = 0; g < BF; ++g) acc4[wv][g][lane] = acc[g];
    }
    __syncthreads();

    for (int i = tid; i < BF * CDIM; i += 256) {
        int g  = i / CDIM;
        int c2 = i - g * CDIM;
        int f = fbase + g;
        if (f < N) {
            float v = acc4[0][g][c2] + acc4[1][g][c2] + acc4[2][g][c2] + acc4[3][g][c2];
            out[(size_t)f * CDIM + c2] = v + b2[c2];
        }
    }
}

extern "C" void kernel_launch(void* const* d_in, const int* in_sizes, int n_in,
                              void* d_out, int out_size, void* d_ws, size_t ws_size,
                              hipStream_t stream) {
    const int*   fr  = (const int*)d_in[0];
    const int*   to  = (const int*)d_in[1];
    const int*   rel = (const int*)d_in[2];
    const float* w1  = (const float*)d_in[3];
    const float* w2  = (const float*)d_in[4];
    const float* b1  = (const float*)d_in[5];
    const float* b2  = (const float*)d_in[6];
    float* out = (float*)d_out;

    const int T  = in_sizes[0];
    const int N  = in_sizes[3] / (RP * EDIM);
    const int NB = N * RP;

    // ---- workspace carve (256B aligned)
    char* p = (char*)d_ws;
    auto alloc = [&](size_t bytes) { char* q = p; p += (bytes + 255) & ~(size_t)255; return q; };
    int*   bucket   = (int*)alloc((size_t)NB * 4);        // hist -> cursor (in-place)
    int*   row_ptr  = (int*)alloc(((size_t)NB + 1) * 4);
    int*   partials = (int*)alloc(4096);
    int*   packed   = (int*)alloc((size_t)T * 4);
    float* h        = (float*)alloc((size_t)N * EDIM * 4);

    const int B = 256;
    hipMemsetAsync(bucket, 0, (size_t)NB * 4, stream);
    k_hist<<<(T + B - 1) / B, B, 0, stream>>>(fr, rel, bucket, T);

    const int nblk = (NB + 1023) / 1024;
    k_scan1<<<nblk, 256, 0, stream>>>(bucket, partials, NB);
    k_scan2<<<1, 1024, 0, stream>>>(partials, nblk);
    k_scan3<<<nblk, 256, 0, stream>>>(bucket, partials, row_ptr, bucket, NB);

    k_scatter<<<(T + B - 1) / B, B, 0, stream>>>(fr, to, rel, bucket, packed, T);

    k_h<<<(N + 3) / 4, 256, 0, stream>>>(row_ptr, packed, w1, b1, h, N);

    k_out<<<(N + BF - 1) / BF, 256, 0, stream>>>(row_ptr, packed, h, w2, b2, out, N);
}

// Round 8
// 190.047 us; speedup vs baseline: 2.4629x; 1.0914x over previous
//
#include <hip/hip_runtime.h>

// LGCN_REL_EMB — atomic-free, fused output, LDS-staged gather (round 8).
//   Counting sort by bucket b = fr*16 + rel (row_ptr over 800K buckets).
//   k_h   : wave per f: h[f,:] = relu(b1 + sum_t w*w1[r_t,to_t,:])   (no atomics)
//   k_out : block = 512 thr (8 waves) x 64 f's.
//     Phase A: stage all the block's triples' h rows into LDS, coalesced
//              (8 lanes x float4 = one 128B row; 1KB per wave-instr).
//     Phase B: wave w owns relations {w, w+8}; w2 column in regs (32 loads
//              per ~20 triples); per triple 8 broadcast ds_read_b128 + 32 FMA;
//              per non-empty run one 50-lane ds_add_f32 into acc[64][52].
//     Phase C: coalesced stores (+b2). row_ptr slice pre-staged in LDS.
// Lessons: r2 — scattered multi-atomics => per-line HBM RMW; r4 — coalesced
// atomics floor ~84us; r5 — materialized h2 worse than fusing; r7 — broadcast
// float4 gathers cost ~17-21cyc/VMEM-instr at 16B useful => instruction-
// efficiency is the wall; branchy per-run scalar row_ptr misses serialize.
// NOTE: packs `to` in 16 bits — requires N <= 65536 (N=50000 here).

#define RP 16
#define EDIM 32
#define CDIM 50
#define BF2 64      // f's per k_out block
#define MAXT 416    // staged triples per batch (Poisson(320)+5.4σ; batching anyway)

// ---------- histogram over buckets b = f*RP + r
__global__ void k_hist(const int* __restrict__ fr, const int* __restrict__ rel,
                       int* __restrict__ bucket, int T) {
    int t = blockIdx.x * blockDim.x + threadIdx.x;
    if (t < T) atomicAdd(&bucket[fr[t] * RP + rel[t]], 1);
}

// ---------- 3-kernel exclusive scan over n elements (1024 elems/block)
__global__ void k_scan1(const int* __restrict__ A, int* __restrict__ partials, int n) {
    __shared__ int lds[256];
    int tid = threadIdx.x;
    int base = blockIdx.x * 1024 + tid * 4;
    int s = 0;
    #pragma unroll
    for (int q = 0; q < 4; ++q) { int i = base + q; if (i < n) s += A[i]; }
    lds[tid] = s; __syncthreads();
    for (int off = 128; off > 0; off >>= 1) {
        if (tid < off) lds[tid] += lds[tid + off];
        __syncthreads();
    }
    if (tid == 0) partials[blockIdx.x] = lds[0];
}

__global__ void k_scan2(int* __restrict__ partials, int nblk) {
    __shared__ int lds[1024];
    __shared__ int carry;
    int tid = threadIdx.x;
    if (tid == 0) carry = 0;
    __syncthreads();
    for (int base = 0; base < nblk; base += 1024) {
        int i = base + tid;
        int v = (i < nblk) ? partials[i] : 0;
        lds[tid] = v; __syncthreads();
        for (int off = 1; off < 1024; off <<= 1) {
            int x = (tid >= off) ? lds[tid - off] : 0;
            __syncthreads();
            lds[tid] += x;
            __syncthreads();
        }
        int incl = lds[tid];
        int mycarry = carry;
        if (i < nblk) partials[i] = incl - v + mycarry;
        __syncthreads();
        if (tid == 0) carry = mycarry + lds[1023];
        __syncthreads();
    }
}

__global__ void k_scan3(const int* __restrict__ A, const int* __restrict__ partials,
                        int* __restrict__ row_ptr, int* __restrict__ cursor, int n) {
    __shared__ int lds[256];
    int tid = threadIdx.x;
    int base = blockIdx.x * 1024 + tid * 4;
    int v[4]; int s = 0;
    #pragma unroll
    for (int q = 0; q < 4; ++q) { int i = base + q; v[q] = (i < n) ? A[i] : 0; s += v[q]; }
    lds[tid] = s; __syncthreads();
    for (int off = 1; off < 256; off <<= 1) {
        int x = (tid >= off) ? lds[tid - off] : 0;
        __syncthreads();
        lds[tid] += x;
        __syncthreads();
    }
    int p = lds[tid] - s + partials[blockIdx.x];
    #pragma unroll
    for (int q = 0; q < 4; ++q) {
        int i = base + q;
        if (i < n) {
            row_ptr[i] = p;
            cursor[i] = p;
            if (i == n - 1) row_ptr[n] = p + v[q];
            p += v[q];
        }
    }
}

// ---------- scatter payload (rel<<16 | to) into sorted order
__global__ void k_scatter(const int* __restrict__ fr, const int* __restrict__ to,
                          const int* __restrict__ rel, int* __restrict__ cursor,
                          int* __restrict__ packed, int T) {
    int t = blockIdx.x * blockDim.x + threadIdx.x;
    if (t < T) {
        int b = fr[t] * RP + rel[t];
        int pos = atomicAdd(&cursor[b], 1);
        packed[pos] = (rel[t] << 16) | to[t];
    }
}

// ---------- h[f,:] = relu(b1 + sum_t (1/len(f,r_t)) * w1[r_t, to_t, :])
__global__ __launch_bounds__(256)
void k_h(const int* __restrict__ row_ptr, const int* __restrict__ packed,
         const float* __restrict__ w1, const float* __restrict__ b1,
         float* __restrict__ h, int N) {
    int f = blockIdx.x * 4 + (threadIdx.x >> 6);
    if (f >= N) return;
    int lane = threadIdx.x & 63;
    int half = lane >> 5;
    int e = lane & 31;
    int s    = row_ptr[f * RP];
    int eend = row_ptr[f * RP + RP];
    float acc = 0.f;
    for (int j = s + half; j < eend; j += 2) {
        int p = packed[j];
        int r = p >> 16, o = p & 0xFFFF;
        int rb = f * RP + r;
        float w = 1.0f / (float)(row_ptr[rb + 1] - row_ptr[rb]);
        acc += w * w1[((size_t)r * N + o) * EDIM + e];
    }
    acc += __shfl_xor(acc, 32, 64);
    if (lane < 32) h[(size_t)f * EDIM + e] = fmaxf(acc + b1[e], 0.f);
}

// ---------- fused second hop + classifier, no global atomics
__global__ __launch_bounds__(512, 4)
void k_out(const int* __restrict__ row_ptr, const int* __restrict__ packed,
           const float* __restrict__ h, const float* __restrict__ w2,
           const float* __restrict__ b2, float* __restrict__ out, int N) {
    extern __shared__ float lds[];
    float* hstage = lds;                                   // [MAXT][32]
    float* accs   = hstage + MAXT * EDIM;                  // [BF2][52]
    int*   rptr_s = (int*)(accs + BF2 * 52);               // [BF2*RP + 1]

    const int tid   = threadIdx.x;
    const int wid   = tid >> 6;                            // 0..7
    const int lane  = tid & 63;
    const int c     = (lane < CDIM) ? lane : CDIM - 1;
    const int fbase = blockIdx.x * BF2;
    if (fbase >= N) return;
    const int fend  = (fbase + BF2 < N) ? fbase + BF2 : N;
    const int gmax  = fend - fbase;
    const int nrp   = gmax * RP + 1;

    for (int i = tid; i < BF2 * 52; i += 512) accs[i] = 0.f;
    for (int i = tid; i < nrp; i += 512) rptr_s[i] = row_ptr[fbase * RP + i];
    __syncthreads();

    const int jstart = rptr_s[0];
    const int jend   = rptr_s[nrp - 1];

    for (int jb = jstart; jb < jend; jb += MAXT) {
        const int cntb = (jend - jb < MAXT) ? jend - jb : MAXT;

        // Phase A: stage h rows, coalesced (8 lanes x float4 per row)
        for (int base = 0; base < cntb; base += 64) {
            int row = base + (tid >> 3);
            if (row < cntb) {
                int o = packed[jb + row] & 0xFFFF;
                int q = tid & 7;
                float4 hv = *reinterpret_cast<const float4*>(h + (size_t)o * EDIM + q * 4);
                *reinterpret_cast<float4*>(hstage + row * EDIM + q * 4) = hv;
            }
        }
        __syncthreads();

        // Phase B: wave wid handles relations wid and wid+8
        for (int rr = 0; rr < 2; ++rr) {
            const int r = wid + 8 * rr;
            float w2c[EDIM];
            {
                const float* wp = w2 + r * (EDIM * CDIM) + c;
                #pragma unroll
                for (int e = 0; e < EDIM; ++e) w2c[e] = wp[e * CDIM];
            }
            for (int g = 0; g < gmax; ++g) {
                int rb = g * RP + r;
                int s0 = rptr_s[rb], e0 = rptr_s[rb + 1];
                int lo = (s0 > jb) ? s0 : jb;
                int hi = (e0 < jb + cntb) ? e0 : jb + cntb;
                if (lo < hi) {
                    float racc = 0.f;
                    for (int j = lo; j < hi; ++j) {
                        const float4* hp =
                            reinterpret_cast<const float4*>(hstage + (j - jb) * EDIM);
                        #pragma unroll
                        for (int q = 0; q < 8; ++q) {
                            float4 hv = hp[q];
                            racc = fmaf(hv.x, w2c[4 * q + 0], racc);
                            racc = fmaf(hv.y, w2c[4 * q + 1], racc);
                            racc = fmaf(hv.z, w2c[4 * q + 2], racc);
                            racc = fmaf(hv.w, w2c[4 * q + 3], racc);
                        }
                    }
                    float val = racc * (1.0f / (float)(e0 - s0));
                    if (lane < CDIM) atomicAdd(&accs[g * 52 + lane], val);
                }
            }
        }
        __syncthreads();
    }

    // Phase C: coalesced stores
    for (int i = tid; i < gmax * CDIM; i += 512) {
        int g  = i / CDIM;
        int c2 = i - g * CDIM;
        out[(size_t)(fbase + g) * CDIM + c2] = accs[g * 52 + c2] + b2[c2];
    }
}

extern "C" void kernel_launch(void* const* d_in, const int* in_sizes, int n_in,
                              void* d_out, int out_size, void* d_ws, size_t ws_size,
                              hipStream_t stream) {
    const int*   fr  = (const int*)d_in[0];
    const int*   to  = (const int*)d_in[1];
    const int*   rel = (const int*)d_in[2];
    const float* w1  = (const float*)d_in[3];
    const float* w2  = (const float*)d_in[4];
    const float* b1  = (const float*)d_in[5];
    const float* b2  = (const float*)d_in[6];
    float* out = (float*)d_out;

    const int T  = in_sizes[0];
    const int N  = in_sizes[3] / (RP * EDIM);
    const int NB = N * RP;

    // ---- workspace carve (256B aligned)
    char* p = (char*)d_ws;
    auto alloc = [&](size_t bytes) { char* q = p; p += (bytes + 255) & ~(size_t)255; return q; };
    int*   bucket   = (int*)alloc((size_t)NB * 4);        // hist -> cursor (in-place)
    int*   row_ptr  = (int*)alloc(((size_t)NB + 1) * 4);
    int*   partials = (int*)alloc(4096);
    int*   packed   = (int*)alloc((size_t)T * 4);
    float* h        = (float*)alloc((size_t)N * EDIM * 4);

    const int B = 256;
    hipMemsetAsync(bucket, 0, (size_t)NB * 4, stream);
    k_hist<<<(T + B - 1) / B, B, 0, stream>>>(fr, rel, bucket, T);

    const int nblk = (NB + 1023) / 1024;
    k_scan1<<<nblk, 256, 0, stream>>>(bucket, partials, NB);
    k_scan2<<<1, 1024, 0, stream>>>(partials, nblk);
    k_scan3<<<nblk, 256, 0, stream>>>(bucket, partials, row_ptr, bucket, NB);

    k_scatter<<<(T + B - 1) / B, B, 0, stream>>>(fr, to, rel, bucket, packed, T);

    k_h<<<(N + 3) / 4, 256, 0, stream>>>(row_ptr, packed, w1, b1, h, N);

    const size_t lds_bytes = (size_t)(MAXT * EDIM + BF2 * 52) * 4
                           + (size_t)(BF2 * RP + 1) * 4;   // 66,560 + 4,100 B
    k_out<<<(N + BF2 - 1) / BF2, 512, lds_bytes, stream>>>(
        row_ptr, packed, h, w2, b2, out, N);
}

// Round 9
// 122.915 us; speedup vs baseline: 3.8081x; 1.5462x over previous
//
#include <hip/hip_runtime.h>

// LGCN_REL_EMB — atomic-free sort + fused MFMA output (round 9).
//   Counting sort by bucket b = fr*16 + rel (row_ptr over 800K buckets).
//   k_h    : wave per f: h[f,:] = relu(b1 + sum_t w*w1[r_t,to_t,:])  (no atomics)
//   k_w2bf : prep w2^T as bf16 [r][c(64, zero-pad)][k(32)]  (B-frags contiguous)
//   k_out  : block = 64 f's, 512 thr. Two phases of 8 relations:
//     stage: per (f,r) run, 8 lanes aggregate h rows (f32 regs), scale 1/len,
//            cvt bf16 -> LDS h2s[8][64][APAD]  (dense; empty runs write 0)
//     mfma : wave (fi,ch) owns 16f x 32c; 16 r-iters of mfma_f32_16x16x32_bf16
//            accumulate in regs; epilogue: direct stores + b2.
// Lessons: r2 — scattered multi-atomics => per-line HBM RMW; r4 — coalesced
// atomic floor ~84us; r5 — materialized h2 (204MB HBM) loses to fusing;
// r7/r8 — per-triple broadcast dot = serial 32-FMA chain + empty-run branch
// overhead is latency-bound at any occupancy; MFMA kills both.
// NOTE: packs `to` in 16 bits — requires N <= 65536 (N=50000 here).

#define RP 16
#define EDIM 32
#define CDIM 50
#define BF2 64      // f's per k_out block
#define RHALF 8     // relations per phase
#define APAD 40     // h2s row stride in bf16 (80 B, 16B-aligned)

typedef __attribute__((ext_vector_type(8))) short short8;
typedef __attribute__((ext_vector_type(4))) float f32x4;

static __device__ inline unsigned short f2bf(float f) {
    unsigned u = __builtin_bit_cast(unsigned, f);
    u += 0x7FFF + ((u >> 16) & 1);          // RNE
    return (unsigned short)(u >> 16);
}

// ---------- histogram over buckets b = f*RP + r
__global__ void k_hist(const int* __restrict__ fr, const int* __restrict__ rel,
                       int* __restrict__ bucket, int T) {
    int t = blockIdx.x * blockDim.x + threadIdx.x;
    if (t < T) atomicAdd(&bucket[fr[t] * RP + rel[t]], 1);
}

// ---------- 3-kernel exclusive scan over n elements (1024 elems/block)
__global__ void k_scan1(const int* __restrict__ A, int* __restrict__ partials, int n) {
    __shared__ int lds[256];
    int tid = threadIdx.x;
    int base = blockIdx.x * 1024 + tid * 4;
    int s = 0;
    #pragma unroll
    for (int q = 0; q < 4; ++q) { int i = base + q; if (i < n) s += A[i]; }
    lds[tid] = s; __syncthreads();
    for (int off = 128; off > 0; off >>= 1) {
        if (tid < off) lds[tid] += lds[tid + off];
        __syncthreads();
    }
    if (tid == 0) partials[blockIdx.x] = lds[0];
}

__global__ void k_scan2(int* __restrict__ partials, int nblk) {
    __shared__ int lds[1024];
    __shared__ int carry;
    int tid = threadIdx.x;
    if (tid == 0) carry = 0;
    __syncthreads();
    for (int base = 0; base < nblk; base += 1024) {
        int i = base + tid;
        int v = (i < nblk) ? partials[i] : 0;
        lds[tid] = v; __syncthreads();
        for (int off = 1; off < 1024; off <<= 1) {
            int x = (tid >= off) ? lds[tid - off] : 0;
            __syncthreads();
            lds[tid] += x;
            __syncthreads();
        }
        int incl = lds[tid];
        int mycarry = carry;
        if (i < nblk) partials[i] = incl - v + mycarry;
        __syncthreads();
        if (tid == 0) carry = mycarry + lds[1023];
        __syncthreads();
    }
}

__global__ void k_scan3(const int* __restrict__ A, const int* __restrict__ partials,
                        int* __restrict__ row_ptr, int* __restrict__ cursor, int n) {
    __shared__ int lds[256];
    int tid = threadIdx.x;
    int base = blockIdx.x * 1024 + tid * 4;
    int v[4]; int s = 0;
    #pragma unroll
    for (int q = 0; q < 4; ++q) { int i = base + q; v[q] = (i < n) ? A[i] : 0; s += v[q]; }
    lds[tid] = s; __syncthreads();
    for (int off = 1; off < 256; off <<= 1) {
        int x = (tid >= off) ? lds[tid - off] : 0;
        __syncthreads();
        lds[tid] += x;
        __syncthreads();
    }
    int p = lds[tid] - s + partials[blockIdx.x];
    #pragma unroll
    for (int q = 0; q < 4; ++q) {
        int i = base + q;
        if (i < n) {
            row_ptr[i] = p;
            cursor[i] = p;
            if (i == n - 1) row_ptr[n] = p + v[q];
            p += v[q];
        }
    }
}

// ---------- scatter payload (rel<<16 | to) into sorted order
__global__ void k_scatter(const int* __restrict__ fr, const int* __restrict__ to,
                          const int* __restrict__ rel, int* __restrict__ cursor,
                          int* __restrict__ packed, int T) {
    int t = blockIdx.x * blockDim.x + threadIdx.x;
    if (t < T) {
        int b = fr[t] * RP + rel[t];
        int pos = atomicAdd(&cursor[b], 1);
        packed[pos] = (rel[t] << 16) | to[t];
    }
}

// ---------- h[f,:] = relu(b1 + sum_t (1/len(f,r_t)) * w1[r_t, to_t, :])
__global__ __launch_bounds__(256)
void k_h(const int* __restrict__ row_ptr, const int* __restrict__ packed,
         const float* __restrict__ w1, const float* __restrict__ b1,
         float* __restrict__ h, int N) {
    int f = blockIdx.x * 4 + (threadIdx.x >> 6);
    if (f >= N) return;
    int lane = threadIdx.x & 63;
    int half = lane >> 5;
    int e = lane & 31;
    int s    = row_ptr[f * RP];
    int eend = row_ptr[f * RP + RP];
    float acc = 0.f;
    for (int j = s + half; j < eend; j += 2) {
        int p = packed[j];
        int r = p >> 16, o = p & 0xFFFF;
        int rb = f * RP + r;
        float w = 1.0f / (float)(row_ptr[rb + 1] - row_ptr[rb]);
        acc += w * w1[((size_t)r * N + o) * EDIM + e];
    }
    acc += __shfl_xor(acc, 32, 64);
    if (lane < 32) h[(size_t)f * EDIM + e] = fmaxf(acc + b1[e], 0.f);
}

// ---------- prep: w2bfT[r][c][k] = bf16(w2[r][k][c]), c zero-padded to 64
__global__ void k_w2bf(const float* __restrict__ w2, unsigned short* __restrict__ w2bfT) {
    int idx = blockIdx.x * 256 + threadIdx.x;    // 16*64*32 = 32768
    if (idx >= RP * 64 * EDIM) return;
    int r = idx >> 11;
    int c = (idx >> 5) & 63;
    int k = idx & 31;
    float v = (c < CDIM) ? w2[(r * EDIM + k) * CDIM + c] : 0.f;
    w2bfT[idx] = f2bf(v);
}

// ---------- fused second hop + classifier via MFMA, no atomics
__global__ __launch_bounds__(512)
void k_out(const int* __restrict__ row_ptr, const int* __restrict__ packed,
           const float* __restrict__ h, const unsigned short* __restrict__ w2bfT,
           const float* __restrict__ b2, float* __restrict__ out, int N) {
    __shared__ unsigned short h2s[RHALF * BF2 * APAD];   // 40,960 B
    __shared__ int rptr_s[BF2 * RP + 1];                 //  4,100 B

    const int tid   = threadIdx.x;
    const int fbase = blockIdx.x * BF2;
    const int gmax  = (N - fbase < BF2) ? (N - fbase) : BF2;

    const int wid  = tid >> 6;
    const int lane = tid & 63;
    const int fi   = wid >> 1;          // 0..3 : 16-row f-subtile
    const int ch   = wid & 1;           // 0..1 : 32-col c-half
    const int arow = lane & 15;
    const int kg   = lane >> 4;         // 0..3

    for (int i = tid; i < gmax * RP + 1; i += 512)
        rptr_s[i] = row_ptr[fbase * RP + i];
    __syncthreads();

    f32x4 acc0 = {0.f, 0.f, 0.f, 0.f};
    f32x4 acc1 = {0.f, 0.f, 0.f, 0.f};

    for (int ph = 0; ph < 2; ++ph) {
        // ---- stage: 8 rounds; round m = relation ph*8+m, 64 runs x 8 lanes
        const int fl = tid >> 3;        // 0..63 : f-local of this lane's run
        const int q  = tid & 7;         // 0..7  : float4 slot
        for (int m = 0; m < RHALF; ++m) {
            const int r = ph * RHALF + m;
            float4 a = {0.f, 0.f, 0.f, 0.f};
            float inv = 0.f;
            if (fl < gmax) {
                int rb = fl * RP + r;
                int s0 = rptr_s[rb], e0 = rptr_s[rb + 1];
                if (e0 > s0) {
                    for (int j = s0; j < e0; ++j) {
                        int o = packed[j] & 0xFFFF;
                        const float4 hv = *reinterpret_cast<const float4*>(
                            h + (size_t)o * EDIM + q * 4);
                        a.x += hv.x; a.y += hv.y; a.z += hv.z; a.w += hv.w;
                    }
                    inv = 1.0f / (float)(e0 - s0);
                }
            }
            unsigned lo = (unsigned)f2bf(a.x * inv) | ((unsigned)f2bf(a.y * inv) << 16);
            unsigned hi = (unsigned)f2bf(a.z * inv) | ((unsigned)f2bf(a.w * inv) << 16);
            unsigned* dst = reinterpret_cast<unsigned*>(
                h2s + (m * BF2 + fl) * APAD + q * 4);
            dst[0] = lo;
            dst[1] = hi;
        }
        __syncthreads();

        // ---- mfma: 8 r-iters this phase, accumulate into persistent accs
        for (int m = 0; m < RHALF; ++m) {
            const int r = ph * RHALF + m;
            short8 af = *reinterpret_cast<const short8*>(
                h2s + (m * BF2 + fi * 16 + arow) * APAD + kg * 8);
            short8 bf0 = *reinterpret_cast<const short8*>(
                w2bfT + ((r * 64 + (ch * 2 + 0) * 16 + arow) * EDIM) + kg * 8);
            short8 bf1 = *reinterpret_cast<const short8*>(
                w2bfT + ((r * 64 + (ch * 2 + 1) * 16 + arow) * EDIM) + kg * 8);
            acc0 = __builtin_amdgcn_mfma_f32_16x16x32_bf16(af, bf0, acc0, 0, 0, 0);
            acc1 = __builtin_amdgcn_mfma_f32_16x16x32_bf16(af, bf1, acc1, 0, 0, 0);
        }
        __syncthreads();
    }

    // ---- epilogue: C/D layout col=lane&15, row=(lane>>4)*4+i (m89-verified)
    const int c0 = (ch * 2 + 0) * 16 + arow;
    const int c1 = (ch * 2 + 1) * 16 + arow;
    const float bb0 = (c0 < CDIM) ? b2[c0] : 0.f;
    const float bb1 = (c1 < CDIM) ? b2[c1] : 0.f;
    #pragma unroll
    for (int i = 0; i < 4; ++i) {
        int f = fbase + fi * 16 + kg * 4 + i;
        if (f < N) {
            if (c0 < CDIM) out[(size_t)f * CDIM + c0] = acc0[i] + bb0;
            if (c1 < CDIM) out[(size_t)f * CDIM + c1] = acc1[i] + bb1;
        }
    }
}

extern "C" void kernel_launch(void* const* d_in, const int* in_sizes, int n_in,
                              void* d_out, int out_size, void* d_ws, size_t ws_size,
                              hipStream_t stream) {
    const int*   fr  = (const int*)d_in[0];
    const int*   to  = (const int*)d_in[1];
    const int*   rel = (const int*)d_in[2];
    const float* w1  = (const float*)d_in[3];
    const float* w2  = (const float*)d_in[4];
    const float* b1  = (const float*)d_in[5];
    const float* b2  = (const float*)d_in[6];
    float* out = (float*)d_out;

    const int T  = in_sizes[0];
    const int N  = in_sizes[3] / (RP * EDIM);
    const int NB = N * RP;

    // ---- workspace carve (256B aligned)
    char* p = (char*)d_ws;
    auto alloc = [&](size_t bytes) { char* q = p; p += (bytes + 255) & ~(size_t)255; return q; };
    int*            bucket   = (int*)alloc((size_t)NB * 4);   // hist -> cursor
    int*            row_ptr  = (int*)alloc(((size_t)NB + 1) * 4);
    int*            partials = (int*)alloc(4096);
    int*            packed   = (int*)alloc((size_t)T * 4);
    float*          h        = (float*)alloc((size_t)N * EDIM * 4);
    unsigned short* w2bfT    = (unsigned short*)alloc((size_t)RP * 64 * EDIM * 2);

    const int B = 256;
    hipMemsetAsync(bucket, 0, (size_t)NB * 4, stream);
    k_hist<<<(T + B - 1) / B, B, 0, stream>>>(fr, rel, bucket, T);

    const int nblk = (NB + 1023) / 1024;
    k_scan1<<<nblk, 256, 0, stream>>>(bucket, partials, NB);
    k_scan2<<<1, 1024, 0, stream>>>(partials, nblk);
    k_scan3<<<nblk, 256, 0, stream>>>(bucket, partials, row_ptr, bucket, NB);

    k_scatter<<<(T + B - 1) / B, B, 0, stream>>>(fr, to, rel, bucket, packed, T);

    k_w2bf<<<(RP * 64 * EDIM + 255) / 256, 256, 0, stream>>>(w2, w2bfT);

    k_h<<<(N + 3) / 4, 256, 0, stream>>>(row_ptr, packed, w1, b1, h, N);

    k_out<<<(N + BF2 - 1) / BF2, 512, 0, stream>>>(
        row_ptr, packed, h, w2bfT, b2, out, N);
}

// Round 10
// 121.739 us; speedup vs baseline: 3.8449x; 1.0097x over previous
//
#include <hip/hip_runtime.h>

// LGCN_REL_EMB — atomic-free sort + fused MFMA output (round 10).
//   Identical to round 9 except: hipMemsetAsync(bucket) replaced by k_zero
//   (rocclr fillBuffer ran ~60us/replay on a 3.2MB buffer — half the total).
//   Counting sort by bucket b = fr*16 + rel (row_ptr over 800K buckets).
//   k_h    : wave per f: h[f,:] = relu(b1 + sum_t w*w1[r_t,to_t,:])  (no atomics)
//   k_w2bf : prep w2^T as bf16 [r][c(64, zero-pad)][k(32)]
//   k_out  : block = 64 f's, 512 thr; stage (f,r)-aggregated bf16 h2 tile in
//            LDS, then 16 iters of mfma_f32_16x16x32_bf16; direct stores + b2.
// Lessons: r2 — scattered multi-atomics => per-line HBM RMW; r4 — coalesced
// atomic floor ~84us; r5 — materialized h2 loses to fusing; r7/r8 — per-triple
// broadcast dot chains are latency-bound; r9 — runtime memset = 60us/replay.
// NOTE: packs `to` in 16 bits — requires N <= 65536 (N=50000 here).

#define RP 16
#define EDIM 32
#define CDIM 50
#define BF2 64      // f's per k_out block
#define RHALF 8     // relations per phase
#define APAD 40     // h2s row stride in bf16 (80 B, 16B-aligned)

typedef __attribute__((ext_vector_type(8))) short short8;
typedef __attribute__((ext_vector_type(4))) float f32x4;

static __device__ inline unsigned short f2bf(float f) {
    unsigned u = __builtin_bit_cast(unsigned, f);
    u += 0x7FFF + ((u >> 16) & 1);          // RNE
    return (unsigned short)(u >> 16);
}

// ---------- zero bucket (replaces rocclr fillBuffer: 60us -> ~2us)
__global__ void k_zero(int4* __restrict__ p, int n4) {
    int i = blockIdx.x * blockDim.x + threadIdx.x;
    if (i < n4) p[i] = make_int4(0, 0, 0, 0);
}

// ---------- histogram over buckets b = f*RP + r
__global__ void k_hist(const int* __restrict__ fr, const int* __restrict__ rel,
                       int* __restrict__ bucket, int T) {
    int t = blockIdx.x * blockDim.x + threadIdx.x;
    if (t < T) atomicAdd(&bucket[fr[t] * RP + rel[t]], 1);
}

// ---------- 3-kernel exclusive scan over n elements (1024 elems/block)
__global__ void k_scan1(const int* __restrict__ A, int* __restrict__ partials, int n) {
    __shared__ int lds[256];
    int tid = threadIdx.x;
    int base = blockIdx.x * 1024 + tid * 4;
    int s = 0;
    #pragma unroll
    for (int q = 0; q < 4; ++q) { int i = base + q; if (i < n) s += A[i]; }
    lds[tid] = s; __syncthreads();
    for (int off = 128; off > 0; off >>= 1) {
        if (tid < off) lds[tid] += lds[tid + off];
        __syncthreads();
    }
    if (tid == 0) partials[blockIdx.x] = lds[0];
}

__global__ void k_scan2(int* __restrict__ partials, int nblk) {
    __shared__ int lds[1024];
    __shared__ int carry;
    int tid = threadIdx.x;
    if (tid == 0) carry = 0;
    __syncthreads();
    for (int base = 0; base < nblk; base += 1024) {
        int i = base + tid;
        int v = (i < nblk) ? partials[i] : 0;
        lds[tid] = v; __syncthreads();
        for (int off = 1; off < 1024; off <<= 1) {
            int x = (tid >= off) ? lds[tid - off] : 0;
            __syncthreads();
            lds[tid] += x;
            __syncthreads();
        }
        int incl = lds[tid];
        int mycarry = carry;
        if (i < nblk) partials[i] = incl - v + mycarry;
        __syncthreads();
        if (tid == 0) carry = mycarry + lds[1023];
        __syncthreads();
    }
}

__global__ void k_scan3(const int* __restrict__ A, const int* __restrict__ partials,
                        int* __restrict__ row_ptr, int* __restrict__ cursor, int n) {
    __shared__ int lds[256];
    int tid = threadIdx.x;
    int base = blockIdx.x * 1024 + tid * 4;
    int v[4]; int s = 0;
    #pragma unroll
    for (int q = 0; q < 4; ++q) { int i = base + q; v[q] = (i < n) ? A[i] : 0; s += v[q]; }
    lds[tid] = s; __syncthreads();
    for (int off = 1; off < 256; off <<= 1) {
        int x = (tid >= off) ? lds[tid - off] : 0;
        __syncthreads();
        lds[tid] += x;
        __syncthreads();
    }
    int p = lds[tid] - s + partials[blockIdx.x];
    #pragma unroll
    for (int q = 0; q < 4; ++q) {
        int i = base + q;
        if (i < n) {
            row_ptr[i] = p;
            cursor[i] = p;
            if (i == n - 1) row_ptr[n] = p + v[q];
            p += v[q];
        }
    }
}

// ---------- scatter payload (rel<<16 | to) into sorted order
__global__ void k_scatter(const int* __restrict__ fr, const int* __restrict__ to,
                          const int* __restrict__ rel, int* __restrict__ cursor,
                          int* __restrict__ packed, int T) {
    int t = blockIdx.x * blockDim.x + threadIdx.x;
    if (t < T) {
        int b = fr[t] * RP + rel[t];
        int pos = atomicAdd(&cursor[b], 1);
        packed[pos] = (rel[t] << 16) | to[t];
    }
}

// ---------- h[f,:] = relu(b1 + sum_t (1/len(f,r_t)) * w1[r_t, to_t, :])
__global__ __launch_bounds__(256)
void k_h(const int* __restrict__ row_ptr, const int* __restrict__ packed,
         const float* __restrict__ w1, const float* __restrict__ b1,
         float* __restrict__ h, int N) {
    int f = blockIdx.x * 4 + (threadIdx.x >> 6);
    if (f >= N) return;
    int lane = threadIdx.x & 63;
    int half = lane >> 5;
    int e = lane & 31;
    int s    = row_ptr[f * RP];
    int eend = row_ptr[f * RP + RP];
    float acc = 0.f;
    for (int j = s + half; j < eend; j += 2) {
        int p = packed[j];
        int r = p >> 16, o = p & 0xFFFF;
        int rb = f * RP + r;
        float w = 1.0f / (float)(row_ptr[rb + 1] - row_ptr[rb]);
        acc += w * w1[((size_t)r * N + o) * EDIM + e];
    }
    acc += __shfl_xor(acc, 32, 64);
    if (lane < 32) h[(size_t)f * EDIM + e] = fmaxf(acc + b1[e], 0.f);
}

// ---------- prep: w2bfT[r][c][k] = bf16(w2[r][k][c]), c zero-padded to 64
__global__ void k_w2bf(const float* __restrict__ w2, unsigned short* __restrict__ w2bfT) {
    int idx = blockIdx.x * 256 + threadIdx.x;    // 16*64*32 = 32768
    if (idx >= RP * 64 * EDIM) return;
    int r = idx >> 11;
    int c = (idx >> 5) & 63;
    int k = idx & 31;
    float v = (c < CDIM) ? w2[(r * EDIM + k) * CDIM + c] : 0.f;
    w2bfT[idx] = f2bf(v);
}

// ---------- fused second hop + classifier via MFMA, no atomics
__global__ __launch_bounds__(512)
void k_out(const int* __restrict__ row_ptr, const int* __restrict__ packed,
           const float* __restrict__ h, const unsigned short* __restrict__ w2bfT,
           const float* __restrict__ b2, float* __restrict__ out, int N) {
    __shared__ unsigned short h2s[RHALF * BF2 * APAD];   // 40,960 B
    __shared__ int rptr_s[BF2 * RP + 1];                 //  4,100 B

    const int tid   = threadIdx.x;
    const int fbase = blockIdx.x * BF2;
    const int gmax  = (N - fbase < BF2) ? (N - fbase) : BF2;

    const int wid  = tid >> 6;
    const int lane = tid & 63;
    const int fi   = wid >> 1;          // 0..3 : 16-row f-subtile
    const int ch   = wid & 1;           // 0..1 : 32-col c-half
    const int arow = lane & 15;
    const int kg   = lane >> 4;         // 0..3

    for (int i = tid; i < gmax * RP + 1; i += 512)
        rptr_s[i] = row_ptr[fbase * RP + i];
    __syncthreads();

    f32x4 acc0 = {0.f, 0.f, 0.f, 0.f};
    f32x4 acc1 = {0.f, 0.f, 0.f, 0.f};

    for (int ph = 0; ph < 2; ++ph) {
        // ---- stage: 8 rounds; round m = relation ph*8+m, 64 runs x 8 lanes
        const int fl = tid >> 3;        // 0..63 : f-local of this lane's run
        const int q  = tid & 7;         // 0..7  : float4 slot
        for (int m = 0; m < RHALF; ++m) {
            const int r = ph * RHALF + m;
            float4 a = {0.f, 0.f, 0.f, 0.f};
            float inv = 0.f;
            if (fl < gmax) {
                int rb = fl * RP + r;
                int s0 = rptr_s[rb], e0 = rptr_s[rb + 1];
                if (e0 > s0) {
                    for (int j = s0; j < e0; ++j) {
                        int o = packed[j] & 0xFFFF;
                        const float4 hv = *reinterpret_cast<const float4*>(
                            h + (size_t)o * EDIM + q * 4);
                        a.x += hv.x; a.y += hv.y; a.z += hv.z; a.w += hv.w;
                    }
                    inv = 1.0f / (float)(e0 - s0);
                }
            }
            unsigned lo = (unsigned)f2bf(a.x * inv) | ((unsigned)f2bf(a.y * inv) << 16);
            unsigned hi = (unsigned)f2bf(a.z * inv) | ((unsigned)f2bf(a.w * inv) << 16);
            unsigned* dst = reinterpret_cast<unsigned*>(
                h2s + (m * BF2 + fl) * APAD + q * 4);
            dst[0] = lo;
            dst[1] = hi;
        }
        __syncthreads();

        // ---- mfma: 8 r-iters this phase, accumulate into persistent accs
        for (int m = 0; m < RHALF; ++m) {
            const int r = ph * RHALF + m;
            short8 af = *reinterpret_cast<const short8*>(
                h2s + (m * BF2 + fi * 16 + arow) * APAD + kg * 8);
            short8 bf0 = *reinterpret_cast<const short8*>(
                w2bfT + ((r * 64 + (ch * 2 + 0) * 16 + arow) * EDIM) + kg * 8);
            short8 bf1 = *reinterpret_cast<const short8*>(
                w2bfT + ((r * 64 + (ch * 2 + 1) * 16 + arow) * EDIM) + kg * 8);
            acc0 = __builtin_amdgcn_mfma_f32_16x16x32_bf16(af, bf0, acc0, 0, 0, 0);
            acc1 = __builtin_amdgcn_mfma_f32_16x16x32_bf16(af, bf1, acc1, 0, 0, 0);
        }
        __syncthreads();
    }

    // ---- epilogue: C/D layout col=lane&15, row=(lane>>4)*4+i (m89-verified)
    const int c0 = (ch * 2 + 0) * 16 + arow;
    const int c1 = (ch * 2 + 1) * 16 + arow;
    const float bb0 = (c0 < CDIM) ? b2[c0] : 0.f;
    const float bb1 = (c1 < CDIM) ? b2[c1] : 0.f;
    #pragma unroll
    for (int i = 0; i < 4; ++i) {
        int f = fbase + fi * 16 + kg * 4 + i;
        if (f < N) {
            if (c0 < CDIM) out[(size_t)f * CDIM + c0] = acc0[i] + bb0;
            if (c1 < CDIM) out[(size_t)f * CDIM + c1] = acc1[i] + bb1;
        }
    }
}

extern "C" void kernel_launch(void* const* d_in, const int* in_sizes, int n_in,
                              void* d_out, int out_size, void* d_ws, size_t ws_size,
                              hipStream_t stream) {
    const int*   fr  = (const int*)d_in[0];
    const int*   to  = (const int*)d_in[1];
    const int*   rel = (const int*)d_in[2];
    const float* w1  = (const float*)d_in[3];
    const float* w2  = (const float*)d_in[4];
    const float* b1  = (const float*)d_in[5];
    const float* b2  = (const float*)d_in[6];
    float* out = (float*)d_out;

    const int T  = in_sizes[0];
    const int N  = in_sizes[3] / (RP * EDIM);
    const int NB = N * RP;

    // ---- workspace carve (256B aligned)
    char* p = (char*)d_ws;
    auto alloc = [&](size_t bytes) { char* q = p; p += (bytes + 255) & ~(size_t)255; return q; };
    int*            bucket   = (int*)alloc((size_t)NB * 4);   // hist -> cursor
    int*            row_ptr  = (int*)alloc(((size_t)NB + 1) * 4);
    int*            partials = (int*)alloc(4096);
    int*            packed   = (int*)alloc((size_t)T * 4);
    float*          h        = (float*)alloc((size_t)N * EDIM * 4);
    unsigned short* w2bfT    = (unsigned short*)alloc((size_t)RP * 64 * EDIM * 2);

    const int B = 256;
    const int n4 = NB / 4;   // NB = 800000, divisible by 4
    k_zero<<<(n4 + B - 1) / B, B, 0, stream>>>((int4*)bucket, n4);
    k_hist<<<(T + B - 1) / B, B, 0, stream>>>(fr, rel, bucket, T);

    const int nblk = (NB + 1023) / 1024;
    k_scan1<<<nblk, 256, 0, stream>>>(bucket, partials, NB);
    k_scan2<<<1, 1024, 0, stream>>>(partials, nblk);
    k_scan3<<<nblk, 256, 0, stream>>>(bucket, partials, row_ptr, bucket, NB);

    k_scatter<<<(T + B - 1) / B, B, 0, stream>>>(fr, to, rel, bucket, packed, T);

    k_w2bf<<<(RP * 64 * EDIM + 255) / 256, 256, 0, stream>>>(w2, w2bfT);

    k_h<<<(N + 3) / 4, 256, 0, stream>>>(row_ptr, packed, w1, b1, h, N);

    k_out<<<(N + BF2 - 1) / BF2, 512, 0, stream>>>(
        row_ptr, packed, h, w2bfT, b2, out, N);
}

// Round 11
// 105.037 us; speedup vs baseline: 4.4563x; 1.1590x over previous
//
#include <hip/hip_runtime.h>

// LGCN_REL_EMB — atomic-free sort + fused MFMA output (round 11).
//   Counting sort by bucket b = fr*16 + rel (row_ptr over 800K buckets).
//   k_zero : zero bucket + prep w2^T bf16 [r][c(64,zpad)][k(32)]  (fused)
//   k_hist : bucket histogram
//   k_scan1: per-1024-chunk sums -> partials
//   k_scanB: own-prefix over partials (block reduce) + intra-chunk exclusive
//            scan -> row_ptr, cursor (fused old scan2+scan3)
//   k_scatter: packed[pos] = rel<<16 | to
//   k_h    : block=64 f's, 8 lanes/f: h_bf16[f,:] = relu(b1 + sum w*w1[r,to,:])
//   k_out  : block=64 f's, 512 thr; per r-phase: batched COALESCED LDS staging
//            of all triples' bf16 h rows (no dependent gathers), register
//            aggregation per (f,r), bf16 h2 tile -> 16x mfma_f32_16x16x32_bf16.
// Lessons: r2 scattered atomics=HBM RMW; r4 coalesced-atomic floor 84us;
// r5 materialized h2 loses; r7/r8 dependent broadcast gathers are latency-
// bound; r9/r10 the ~59us top entries are the harness's 400MB ws poison —
// our pipeline is ~60us of long tail, so shrink every stage + launch count.
// NOTE: packs `to` in 16 bits — requires N <= 65536 (N=50000 here).

#define RP 16
#define EDIM 32
#define CDIM 50
#define BF2 64      // f's per block (k_h, k_out)
#define RHALF 8     // relations per phase in k_out
#define APAD 40     // h2s row stride in bf16 (80B; MFMA b128 reads land on 8
                    // distinct bank-starts -> inherent-minimum bank cycles)
#define MAXT 416    // staged triples per batch

typedef __attribute__((ext_vector_type(8))) short short8;
typedef __attribute__((ext_vector_type(4))) float f32x4;

static __device__ inline unsigned short f2bf(float f) {
    unsigned u = __builtin_bit_cast(unsigned, f);
    u += 0x7FFF + ((u >> 16) & 1);          // RNE
    return (unsigned short)(u >> 16);
}
static __device__ inline float bf2f_lo(unsigned u) {
    return __builtin_bit_cast(float, u << 16);
}
static __device__ inline float bf2f_hi(unsigned u) {
    return __builtin_bit_cast(float, u & 0xFFFF0000u);
}

// ---------- zero bucket + w2 transpose/convert (fused)
__global__ void k_zero(int4* __restrict__ p, int n4,
                       const float* __restrict__ w2,
                       unsigned short* __restrict__ w2bfT) {
    int gid = blockIdx.x * blockDim.x + threadIdx.x;
    if (gid < n4) p[gid] = make_int4(0, 0, 0, 0);
    if (gid < RP * 64 * EDIM) {
        int r = gid >> 11;
        int c = (gid >> 5) & 63;
        int k = gid & 31;
        float v = (c < CDIM) ? w2[(r * EDIM + k) * CDIM + c] : 0.f;
        w2bfT[gid] = f2bf(v);
    }
}

// ---------- histogram over buckets b = f*RP + r
__global__ void k_hist(const int* __restrict__ fr, const int* __restrict__ rel,
                       int* __restrict__ bucket, int T) {
    int t = blockIdx.x * blockDim.x + threadIdx.x;
    if (t < T) atomicAdd(&bucket[fr[t] * RP + rel[t]], 1);
}

// ---------- chunk sums (1024 elems/block)
__global__ void k_scan1(const int* __restrict__ A, int* __restrict__ partials, int n) {
    __shared__ int lds[256];
    int tid = threadIdx.x;
    int base = blockIdx.x * 1024 + tid * 4;
    int s = 0;
    #pragma unroll
    for (int q = 0; q < 4; ++q) { int i = base + q; if (i < n) s += A[i]; }
    lds[tid] = s; __syncthreads();
    for (int off = 128; off > 0; off >>= 1) {
        if (tid < off) lds[tid] += lds[tid + off];
        __syncthreads();
    }
    if (tid == 0) partials[blockIdx.x] = lds[0];
}

// ---------- fused scan2+scan3: own-prefix by reduction + intra-chunk exscan
__global__ void k_scanB(const int* __restrict__ A, const int* __restrict__ partials,
                        int* __restrict__ row_ptr, int* __restrict__ cursor, int n) {
    __shared__ int lds[256];
    __shared__ int sbase;
    int tid = threadIdx.x;
    int c = blockIdx.x;

    // base = sum partials[0..c)
    int ps = 0;
    for (int i = tid; i < c; i += 256) ps += partials[i];
    lds[tid] = ps; __syncthreads();
    for (int off = 128; off > 0; off >>= 1) {
        if (tid < off) lds[tid] += lds[tid + off];
        __syncthreads();
    }
    if (tid == 0) sbase = lds[0];
    __syncthreads();
    int base0 = sbase;
    __syncthreads();

    // intra-chunk exclusive scan (4 elems/thread)
    int gbase = c * 1024 + tid * 4;
    int v[4]; int s = 0;
    #pragma unroll
    for (int q = 0; q < 4; ++q) { int i = gbase + q; v[q] = (i < n) ? A[i] : 0; s += v[q]; }
    lds[tid] = s; __syncthreads();
    for (int off = 1; off < 256; off <<= 1) {
        int x = (tid >= off) ? lds[tid - off] : 0;
        __syncthreads();
        lds[tid] += x;
        __syncthreads();
    }
    int p = lds[tid] - s + base0;
    #pragma unroll
    for (int q = 0; q < 4; ++q) {
        int i = gbase + q;
        if (i < n) {
            row_ptr[i] = p;
            cursor[i] = p;
            if (i == n - 1) row_ptr[n] = p + v[q];
            p += v[q];
        }
    }
}

// ---------- scatter payload (rel<<16 | to) into sorted order
__global__ void k_scatter(const int* __restrict__ fr, const int* __restrict__ to,
                          const int* __restrict__ rel, int* __restrict__ cursor,
                          int* __restrict__ packed, int T) {
    int t = blockIdx.x * blockDim.x + threadIdx.x;
    if (t < T) {
        int b = fr[t] * RP + rel[t];
        int pos = atomicAdd(&cursor[b], 1);
        packed[pos] = (rel[t] << 16) | to[t];
    }
}

// ---------- h_bf16[f,:] = relu(b1 + sum_r (1/len) sum_run w1[r, to, :])
// block = 64 f's, 8 lanes per f (lane q owns 4 e-slots), rptr staged in LDS.
__global__ __launch_bounds__(512)
void k_h(const int* __restrict__ row_ptr, const int* __restrict__ packed,
         const float* __restrict__ w1, const float* __restrict__ b1,
         unsigned short* __restrict__ hbf, int N) {
    __shared__ int rptr_s[BF2 * RP + 1];
    const int tid = threadIdx.x;
    const int fbase = blockIdx.x * BF2;
    const int gmax = (N - fbase < BF2) ? (N - fbase) : BF2;

    for (int i = tid; i < gmax * RP + 1; i += 512)
        rptr_s[i] = row_ptr[fbase * RP + i];
    __syncthreads();

    const int fl = tid >> 3;
    const int q  = tid & 7;
    if (fl >= gmax) return;
    const int f = fbase + fl;

    float a0 = 0.f, a1 = 0.f, a2 = 0.f, a3 = 0.f;
    for (int r = 0; r < RP; ++r) {
        int rb = fl * RP + r;
        int s0 = rptr_s[rb], e0 = rptr_s[rb + 1];
        if (s0 < e0) {
            float r0 = 0.f, r1 = 0.f, r2 = 0.f, r3 = 0.f;
            for (int j = s0; j < e0; ++j) {
                int o = packed[j] & 0xFFFF;
                const float4 v = *reinterpret_cast<const float4*>(
                    w1 + ((size_t)r * N + o) * EDIM + q * 4);
                r0 += v.x; r1 += v.y; r2 += v.z; r3 += v.w;
            }
            float inv = 1.0f / (float)(e0 - s0);
            a0 += r0 * inv; a1 += r1 * inv; a2 += r2 * inv; a3 += r3 * inv;
        }
    }
    const float4 bb = *reinterpret_cast<const float4*>(b1 + q * 4);
    a0 = fmaxf(a0 + bb.x, 0.f);
    a1 = fmaxf(a1 + bb.y, 0.f);
    a2 = fmaxf(a2 + bb.z, 0.f);
    a3 = fmaxf(a3 + bb.w, 0.f);
    uint2 w;
    w.x = (unsigned)f2bf(a0) | ((unsigned)f2bf(a1) << 16);
    w.y = (unsigned)f2bf(a2) | ((unsigned)f2bf(a3) << 16);
    *reinterpret_cast<uint2*>(hbf + (size_t)f * EDIM + q * 4) = w;
}

// ---------- fused second hop + classifier via MFMA, no atomics
// Per r-phase: batched coalesced LDS staging of bf16 h rows (independent
// loads), register aggregation per (f,r), bf16 h2 tile, 8 r-iters of MFMA.
__global__ __launch_bounds__(512)
void k_out(const int* __restrict__ row_ptr, const int* __restrict__ packed,
           const unsigned short* __restrict__ hbf,
           const unsigned short* __restrict__ w2bfT,
           const float* __restrict__ b2, float* __restrict__ out, int N) {
    extern __shared__ char smem[];
    unsigned short* hstage = (unsigned short*)smem;            // [MAXT][32] bf16 = 26,624B
    unsigned short* h2s    = hstage + MAXT * EDIM;             // [8][64][APAD]  = 40,960B
    int*            rptr_s = (int*)(h2s + RHALF * BF2 * APAD); // 4,100B

    const int tid   = threadIdx.x;
    const int fbase = blockIdx.x * BF2;
    const int gmax  = (N - fbase < BF2) ? (N - fbase) : BF2;

    const int wid  = tid >> 6;
    const int lane = tid & 63;
    const int fi   = wid >> 1;          // 0..3 : 16-row f-subtile
    const int ch   = wid & 1;           // 0..1 : 32-col c-half
    const int arow = lane & 15;
    const int kg   = lane >> 4;         // 0..3
    const int fl   = tid >> 3;          // 0..63 : group f
    const int q    = tid & 7;           // 0..7  : 4-elem slot

    for (int i = tid; i < gmax * RP + 1; i += 512)
        rptr_s[i] = row_ptr[fbase * RP + i];
    __syncthreads();

    const int jstart = rptr_s[0];
    const int jend   = rptr_s[gmax * RP];

    f32x4 acc0 = {0.f, 0.f, 0.f, 0.f};
    f32x4 acc1 = {0.f, 0.f, 0.f, 0.f};

    for (int ph = 0; ph < 2; ++ph) {
        float aggr[RHALF][4];
        #pragma unroll
        for (int m = 0; m < RHALF; ++m) {
            aggr[m][0] = 0.f; aggr[m][1] = 0.f; aggr[m][2] = 0.f; aggr[m][3] = 0.f;
        }

        for (int jb = jstart; jb < jend; jb += MAXT) {
            const int cntb = (jend - jb < MAXT) ? jend - jb : MAXT;

            // stage: coalesced, latency-independent bf16 row copies
            for (int row = fl; row < cntb; row += 64) {
                int o = packed[jb + row] & 0xFFFF;
                *reinterpret_cast<uint2*>(hstage + row * EDIM + q * 4) =
                    *reinterpret_cast<const uint2*>(hbf + (size_t)o * EDIM + q * 4);
            }
            __syncthreads();

            // aggregate runs from LDS into registers
            if (fl < gmax) {
                #pragma unroll
                for (int m = 0; m < RHALF; ++m) {
                    int rb = fl * RP + ph * RHALF + m;
                    int s0 = rptr_s[rb], e0 = rptr_s[rb + 1];
                    int lo = (s0 > jb) ? s0 : jb;
                    int hi = (e0 < jb + cntb) ? e0 : jb + cntb;
                    for (int j = lo; j < hi; ++j) {
                        uint2 hv = *reinterpret_cast<const uint2*>(
                            hstage + (j - jb) * EDIM + q * 4);
                        aggr[m][0] += bf2f_lo(hv.x);
                        aggr[m][1] += bf2f_hi(hv.x);
                        aggr[m][2] += bf2f_lo(hv.y);
                        aggr[m][3] += bf2f_hi(hv.y);
                    }
                }
            }
            __syncthreads();   // before next batch overwrites hstage
        }

        // write bf16 h2 tile (zeros for pad rows)
        uint2 zz; zz.x = 0u; zz.y = 0u;
        #pragma unroll
        for (int m = 0; m < RHALF; ++m) {
            uint2 w = zz;
            if (fl < gmax) {
                int rb = fl * RP + ph * RHALF + m;
                int s0 = rptr_s[rb], e0 = rptr_s[rb + 1];
                float inv = (e0 > s0) ? 1.0f / (float)(e0 - s0) : 0.0f;
                w.x = (unsigned)f2bf(aggr[m][0] * inv) |
                      ((unsigned)f2bf(aggr[m][1] * inv) << 16);
                w.y = (unsigned)f2bf(aggr[m][2] * inv) |
                      ((unsigned)f2bf(aggr[m][3] * inv) << 16);
            }
            *reinterpret_cast<uint2*>(h2s + (m * BF2 + fl) * APAD + q * 4) = w;
        }
        __syncthreads();

        // MFMA: 8 r-iters this phase
        for (int m = 0; m < RHALF; ++m) {
            const int r = ph * RHALF + m;
            short8 af = *reinterpret_cast<const short8*>(
                h2s + (m * BF2 + fi * 16 + arow) * APAD + kg * 8);
            short8 bf0 = *reinterpret_cast<const short8*>(
                w2bfT + ((r * 64 + (ch * 2 + 0) * 16 + arow) * EDIM) + kg * 8);
            short8 bf1 = *reinterpret_cast<const short8*>(
                w2bfT + ((r * 64 + (ch * 2 + 1) * 16 + arow) * EDIM) + kg * 8);
            acc0 = __builtin_amdgcn_mfma_f32_16x16x32_bf16(af, bf0, acc0, 0, 0, 0);
            acc1 = __builtin_amdgcn_mfma_f32_16x16x32_bf16(af, bf1, acc1, 0, 0, 0);
        }
        __syncthreads();   // before next phase rewrites h2s
    }

    // epilogue: C/D layout col=lane&15, row=(lane>>4)*4+i (m89-verified)
    const int c0 = (ch * 2 + 0) * 16 + arow;
    const int c1 = (ch * 2 + 1) * 16 + arow;
    const float bb0 = (c0 < CDIM) ? b2[c0] : 0.f;
    const float bb1 = (c1 < CDIM) ? b2[c1] : 0.f;
    #pragma unroll
    for (int i = 0; i < 4; ++i) {
        int f = fbase + fi * 16 + kg * 4 + i;
        if (f < N) {
            if (c0 < CDIM) out[(size_t)f * CDIM + c0] = acc0[i] + bb0;
            if (c1 < CDIM) out[(size_t)f * CDIM + c1] = acc1[i] + bb1;
        }
    }
}

extern "C" void kernel_launch(void* const* d_in, const int* in_sizes, int n_in,
                              void* d_out, int out_size, void* d_ws, size_t ws_size,
                              hipStream_t stream) {
    const int*   fr  = (const int*)d_in[0];
    const int*   to  = (const int*)d_in[1];
    const int*   rel = (const int*)d_in[2];
    const float* w1  = (const float*)d_in[3];
    const float* w2  = (const float*)d_in[4];
    const float* b1  = (const float*)d_in[5];
    const float* b2  = (const float*)d_in[6];
    float* out = (float*)d_out;

    const int T  = in_sizes[0];
    const int N  = in_sizes[3] / (RP * EDIM);
    const int NB = N * RP;

    // ---- workspace carve (256B aligned)
    char* p = (char*)d_ws;
    auto alloc = [&](size_t bytes) { char* q = p; p += (bytes + 255) & ~(size_t)255; return q; };
    int*            bucket   = (int*)alloc((size_t)NB * 4);   // hist -> cursor
    int*            row_ptr  = (int*)alloc(((size_t)NB + 1) * 4);
    int*            partials = (int*)alloc(4096);
    int*            packed   = (int*)alloc((size_t)T * 4);
    unsigned short* hbf      = (unsigned short*)alloc((size_t)N * EDIM * 2);
    unsigned short* w2bfT    = (unsigned short*)alloc((size_t)RP * 64 * EDIM * 2);

    const int B = 256;
    const int n4 = (NB + 3) / 4;
    k_zero<<<(n4 + B - 1) / B, B, 0, stream>>>((int4*)bucket, n4, w2, w2bfT);
    k_hist<<<(T + B - 1) / B, B, 0, stream>>>(fr, rel, bucket, T);

    const int nblk = (NB + 1023) / 1024;
    k_scan1<<<nblk, 256, 0, stream>>>(bucket, partials, NB);
    k_scanB<<<nblk, 256, 0, stream>>>(bucket, partials, row_ptr, bucket, NB);

    k_scatter<<<(T + B - 1) / B, B, 0, stream>>>(fr, to, rel, bucket, packed, T);

    k_h<<<(N + BF2 - 1) / BF2, 512, 0, stream>>>(row_ptr, packed, w1, b1, hbf, N);

    const size_t lds_bytes = (size_t)MAXT * EDIM * 2 + (size_t)RHALF * BF2 * APAD * 2
                           + (size_t)(BF2 * RP + 1) * 4;   // 71,684 B
    k_out<<<(N + BF2 - 1) / BF2, 512, lds_bytes, stream>>>(
        row_ptr, packed, hbf, w2bfT, b2, out, N);
}

// Round 12
// 103.404 us; speedup vs baseline: 4.5267x; 1.0158x over previous
//
#include <hip/hip_runtime.h>

// LGCN_REL_EMB — atomic-free sort + fused MFMA output (round 12).
//   Counting sort by bucket b = fr*16 + rel (row_ptr over 800K buckets).
//   k_zero : zero bucket + prep w2^T bf16 [r][c(64,zpad)][k(32)]  (fused)
//   k_hist / k_scan1 / k_scanB / k_scatter : sort chain (unchanged from r11)
//   k_h    : block=64 f's, 8 lanes/f, ONE flat j-loop per f (r from payload,
//            weight from LDS inv table) -> independent w1 gathers, no run fences.
//   k_out  : block=64 f's, 512 thr, LDS=49KB (3 blocks/CU): per phase of 8
//            relations, aggregate runs DIRECTLY from global bf16 h (8-lane
//            uint2 = coalesced 64B, L2-resident) into regs, write bf16 h2
//            tile, 8x mfma_f32_16x16x32_bf16. No LDS staging pass at all.
// Lessons: r2 scattered atomics=HBM RMW; r4 coalesced-atomic floor 84us;
// r5 materialized h2 loses; r7/r8 dependent broadcast gathers latency-bound;
// r9/r10 ~59us top-5 entries are harness ws-poison fills (not ours);
// r11 post-mortem: k_out's 71.7KB LDS (2 blocks/CU) + double full-range
// staging was the cost — direct global aggregation beats staging for
// L2-resident h.
// NOTE: packs `to` in 16 bits — requires N <= 65536 (N=50000 here).

#define RP 16
#define EDIM 32
#define CDIM 50
#define BF2 64      // f's per block (k_h, k_out)
#define RHALF 8     // relations per phase in k_out
#define APAD 40     // h2s row stride in bf16 (80B)

typedef __attribute__((ext_vector_type(8))) short short8;
typedef __attribute__((ext_vector_type(4))) float f32x4;

static __device__ inline unsigned short f2bf(float f) {
    unsigned u = __builtin_bit_cast(unsigned, f);
    u += 0x7FFF + ((u >> 16) & 1);          // RNE
    return (unsigned short)(u >> 16);
}
static __device__ inline float bf2f_lo(unsigned u) {
    return __builtin_bit_cast(float, u << 16);
}
static __device__ inline float bf2f_hi(unsigned u) {
    return __builtin_bit_cast(float, u & 0xFFFF0000u);
}

// ---------- zero bucket + w2 transpose/convert (fused)
__global__ void k_zero(int4* __restrict__ p, int n4,
                       const float* __restrict__ w2,
                       unsigned short* __restrict__ w2bfT) {
    int gid = blockIdx.x * blockDim.x + threadIdx.x;
    if (gid < n4) p[gid] = make_int4(0, 0, 0, 0);
    if (gid < RP * 64 * EDIM) {
        int r = gid >> 11;
        int c = (gid >> 5) & 63;
        int k = gid & 31;
        float v = (c < CDIM) ? w2[(r * EDIM + k) * CDIM + c] : 0.f;
        w2bfT[gid] = f2bf(v);
    }
}

// ---------- histogram over buckets b = f*RP + r
__global__ void k_hist(const int* __restrict__ fr, const int* __restrict__ rel,
                       int* __restrict__ bucket, int T) {
    int t = blockIdx.x * blockDim.x + threadIdx.x;
    if (t < T) atomicAdd(&bucket[fr[t] * RP + rel[t]], 1);
}

// ---------- chunk sums (1024 elems/block)
__global__ void k_scan1(const int* __restrict__ A, int* __restrict__ partials, int n) {
    __shared__ int lds[256];
    int tid = threadIdx.x;
    int base = blockIdx.x * 1024 + tid * 4;
    int s = 0;
    #pragma unroll
    for (int q = 0; q < 4; ++q) { int i = base + q; if (i < n) s += A[i]; }
    lds[tid] = s; __syncthreads();
    for (int off = 128; off > 0; off >>= 1) {
        if (tid < off) lds[tid] += lds[tid + off];
        __syncthreads();
    }
    if (tid == 0) partials[blockIdx.x] = lds[0];
}

// ---------- fused scan2+scan3: own-prefix by reduction + intra-chunk exscan
__global__ void k_scanB(const int* __restrict__ A, const int* __restrict__ partials,
                        int* __restrict__ row_ptr, int* __restrict__ cursor, int n) {
    __shared__ int lds[256];
    __shared__ int sbase;
    int tid = threadIdx.x;
    int c = blockIdx.x;

    int ps = 0;
    for (int i = tid; i < c; i += 256) ps += partials[i];
    lds[tid] = ps; __syncthreads();
    for (int off = 128; off > 0; off >>= 1) {
        if (tid < off) lds[tid] += lds[tid + off];
        __syncthreads();
    }
    if (tid == 0) sbase = lds[0];
    __syncthreads();
    int base0 = sbase;
    __syncthreads();

    int gbase = c * 1024 + tid * 4;
    int v[4]; int s = 0;
    #pragma unroll
    for (int q = 0; q < 4; ++q) { int i = gbase + q; v[q] = (i < n) ? A[i] : 0; s += v[q]; }
    lds[tid] = s; __syncthreads();
    for (int off = 1; off < 256; off <<= 1) {
        int x = (tid >= off) ? lds[tid - off] : 0;
        __syncthreads();
        lds[tid] += x;
        __syncthreads();
    }
    int p = lds[tid] - s + base0;
    #pragma unroll
    for (int q = 0; q < 4; ++q) {
        int i = gbase + q;
        if (i < n) {
            row_ptr[i] = p;
            cursor[i] = p;
            if (i == n - 1) row_ptr[n] = p + v[q];
            p += v[q];
        }
    }
}

// ---------- scatter payload (rel<<16 | to) into sorted order
__global__ void k_scatter(const int* __restrict__ fr, const int* __restrict__ to,
                          const int* __restrict__ rel, int* __restrict__ cursor,
                          int* __restrict__ packed, int T) {
    int t = blockIdx.x * blockDim.x + threadIdx.x;
    if (t < T) {
        int b = fr[t] * RP + rel[t];
        int pos = atomicAdd(&cursor[b], 1);
        packed[pos] = (rel[t] << 16) | to[t];
    }
}

// ---------- h_bf16[f,:] = relu(b1 + sum_j inv[r_j] * w1[r_j, to_j, :])
// block = 64 f's, 8 lanes per f; ONE flat j-loop (independent gathers).
__global__ __launch_bounds__(512)
void k_h(const int* __restrict__ row_ptr, const int* __restrict__ packed,
         const float* __restrict__ w1, const float* __restrict__ b1,
         unsigned short* __restrict__ hbf, int N) {
    __shared__ int   rptr_s[BF2 * RP + 1];
    __shared__ float inv_s[BF2 * RP];
    const int tid = threadIdx.x;
    const int fbase = blockIdx.x * BF2;
    const int gmax = (N - fbase < BF2) ? (N - fbase) : BF2;

    for (int i = tid; i < gmax * RP + 1; i += 512)
        rptr_s[i] = row_ptr[fbase * RP + i];
    __syncthreads();
    for (int i = tid; i < gmax * RP; i += 512) {
        int cnt = rptr_s[i + 1] - rptr_s[i];
        inv_s[i] = (cnt > 0) ? 1.0f / (float)cnt : 0.0f;
    }
    __syncthreads();

    const int fl = tid >> 3;
    const int q  = tid & 7;
    if (fl >= gmax) return;
    const int f = fbase + fl;

    const int s0 = rptr_s[fl * RP];
    const int e0 = rptr_s[fl * RP + RP];
    float a0 = 0.f, a1 = 0.f, a2 = 0.f, a3 = 0.f;
    for (int j = s0; j < e0; ++j) {
        int p = packed[j];
        int r = p >> 16, o = p & 0xFFFF;
        float w = inv_s[fl * RP + r];
        const float4 v = *reinterpret_cast<const float4*>(
            w1 + ((size_t)r * N + o) * EDIM + q * 4);
        a0 = fmaf(w, v.x, a0); a1 = fmaf(w, v.y, a1);
        a2 = fmaf(w, v.z, a2); a3 = fmaf(w, v.w, a3);
    }
    const float4 bb = *reinterpret_cast<const float4*>(b1 + q * 4);
    a0 = fmaxf(a0 + bb.x, 0.f);
    a1 = fmaxf(a1 + bb.y, 0.f);
    a2 = fmaxf(a2 + bb.z, 0.f);
    a3 = fmaxf(a3 + bb.w, 0.f);
    uint2 w;
    w.x = (unsigned)f2bf(a0) | ((unsigned)f2bf(a1) << 16);
    w.y = (unsigned)f2bf(a2) | ((unsigned)f2bf(a3) << 16);
    *reinterpret_cast<uint2*>(hbf + (size_t)f * EDIM + q * 4) = w;
}

// ---------- fused second hop + classifier via MFMA, no atomics, no staging
__global__ __launch_bounds__(512)
void k_out(const int* __restrict__ row_ptr, const int* __restrict__ packed,
           const unsigned short* __restrict__ hbf,
           const unsigned short* __restrict__ w2bfT,
           const float* __restrict__ b2, float* __restrict__ out, int N) {
    __shared__ unsigned short h2s[RHALF * BF2 * APAD];   // 40,960 B
    __shared__ int   rptr_s[BF2 * RP + 1];               //  4,100 B
    __shared__ float inv_s[BF2 * RP];                    //  4,096 B

    const int tid   = threadIdx.x;
    const int fbase = blockIdx.x * BF2;
    const int gmax  = (N - fbase < BF2) ? (N - fbase) : BF2;

    const int wid  = tid >> 6;
    const int lane = tid & 63;
    const int fi   = wid >> 1;          // 0..3 : 16-row f-subtile
    const int ch   = wid & 1;           // 0..1 : 32-col c-half
    const int arow = lane & 15;
    const int kg   = lane >> 4;         // 0..3
    const int fl   = tid >> 3;          // 0..63 : group f
    const int q    = tid & 7;           // 0..7  : 4-elem slot

    for (int i = tid; i < gmax * RP + 1; i += 512)
        rptr_s[i] = row_ptr[fbase * RP + i];
    __syncthreads();
    for (int i = tid; i < gmax * RP; i += 512) {
        int cnt = rptr_s[i + 1] - rptr_s[i];
        inv_s[i] = (cnt > 0) ? 1.0f / (float)cnt : 0.0f;
    }
    __syncthreads();

    f32x4 acc0 = {0.f, 0.f, 0.f, 0.f};
    f32x4 acc1 = {0.f, 0.f, 0.f, 0.f};

    for (int ph = 0; ph < 2; ++ph) {
        // aggregate runs directly from global bf16 h (L2-resident);
        // 8 lanes x uint2 per row = coalesced 64B segment.
        #pragma unroll
        for (int m = 0; m < RHALF; ++m) {
            float g0 = 0.f, g1 = 0.f, g2 = 0.f, g3 = 0.f;
            float inv = 0.f;
            if (fl < gmax) {
                int rb = fl * RP + ph * RHALF + m;
                int s0 = rptr_s[rb], e0 = rptr_s[rb + 1];
                inv = inv_s[rb];
                for (int j = s0; j < e0; ++j) {
                    int o = packed[j] & 0xFFFF;
                    uint2 hv = *reinterpret_cast<const uint2*>(
                        hbf + (size_t)o * EDIM + q * 4);
                    g0 += bf2f_lo(hv.x);
                    g1 += bf2f_hi(hv.x);
                    g2 += bf2f_lo(hv.y);
                    g3 += bf2f_hi(hv.y);
                }
            }
            uint2 w;
            w.x = (unsigned)f2bf(g0 * inv) | ((unsigned)f2bf(g1 * inv) << 16);
            w.y = (unsigned)f2bf(g2 * inv) | ((unsigned)f2bf(g3 * inv) << 16);
            *reinterpret_cast<uint2*>(h2s + (m * BF2 + fl) * APAD + q * 4) = w;
        }
        __syncthreads();

        // MFMA: 8 r-iters this phase
        for (int m = 0; m < RHALF; ++m) {
            const int r = ph * RHALF + m;
            short8 af = *reinterpret_cast<const short8*>(
                h2s + (m * BF2 + fi * 16 + arow) * APAD + kg * 8);
            short8 bf0 = *reinterpret_cast<const short8*>(
                w2bfT + ((r * 64 + (ch * 2 + 0) * 16 + arow) * EDIM) + kg * 8);
            short8 bf1 = *reinterpret_cast<const short8*>(
                w2bfT + ((r * 64 + (ch * 2 + 1) * 16 + arow) * EDIM) + kg * 8);
            acc0 = __builtin_amdgcn_mfma_f32_16x16x32_bf16(af, bf0, acc0, 0, 0, 0);
            acc1 = __builtin_amdgcn_mfma_f32_16x16x32_bf16(af, bf1, acc1, 0, 0, 0);
        }
        __syncthreads();   // before next phase rewrites h2s
    }

    // epilogue: C/D layout col=lane&15, row=(lane>>4)*4+i (m89-verified)
    const int c0 = (ch * 2 + 0) * 16 + arow;
    const int c1 = (ch * 2 + 1) * 16 + arow;
    const float bb0 = (c0 < CDIM) ? b2[c0] : 0.f;
    const float bb1 = (c1 < CDIM) ? b2[c1] : 0.f;
    #pragma unroll
    for (int i = 0; i < 4; ++i) {
        int f = fbase + fi * 16 + kg * 4 + i;
        if (f < N) {
            if (c0 < CDIM) out[(size_t)f * CDIM + c0] = acc0[i] + bb0;
            if (c1 < CDIM) out[(size_t)f * CDIM + c1] = acc1[i] + bb1;
        }
    }
}

extern "C" void kernel_launch(void* const* d_in, const int* in_sizes, int n_in,
                              void* d_out, int out_size, void* d_ws, size_t ws_size,
                              hipStream_t stream) {
    const int*   fr  = (const int*)d_in[0];
    const int*   to  = (const int*)d_in[1];
    const int*   rel = (const int*)d_in[2];
    const float* w1  = (const float*)d_in[3];
    const float* w2  = (const float*)d_in[4];
    const float* b1  = (const float*)d_in[5];
    const float* b2  = (const float*)d_in[6];
    float* out = (float*)d_out;

    const int T  = in_sizes[0];
    const int N  = in_sizes[3] / (RP * EDIM);
    const int NB = N * RP;

    // ---- workspace carve (256B aligned)
    char* p = (char*)d_ws;
    auto alloc = [&](size_t bytes) { char* q = p; p += (bytes + 255) & ~(size_t)255; return q; };
    int*            bucket   = (int*)alloc((size_t)NB * 4);   // hist -> cursor
    int*            row_ptr  = (int*)alloc(((size_t)NB + 1) * 4);
    int*            partials = (int*)alloc(4096);
    int*            packed   = (int*)alloc((size_t)T * 4);
    unsigned short* hbf      = (unsigned short*)alloc((size_t)N * EDIM * 2);
    unsigned short* w2bfT    = (unsigned short*)alloc((size_t)RP * 64 * EDIM * 2);

    const int B = 256;
    const int n4 = (NB + 3) / 4;
    k_zero<<<(n4 + B - 1) / B, B, 0, stream>>>((int4*)bucket, n4, w2, w2bfT);
    k_hist<<<(T + B - 1) / B, B, 0, stream>>>(fr, rel, bucket, T);

    const int nblk = (NB + 1023) / 1024;
    k_scan1<<<nblk, 256, 0, stream>>>(bucket, partials, NB);
    k_scanB<<<nblk, 256, 0, stream>>>(bucket, partials, row_ptr, bucket, NB);

    k_scatter<<<(T + B - 1) / B, B, 0, stream>>>(fr, to, rel, bucket, packed, T);

    k_h<<<(N + BF2 - 1) / BF2, 512, 0, stream>>>(row_ptr, packed, w1, b1, hbf, N);

    k_out<<<(N + BF2 - 1) / BF2, 512, 0, stream>>>(
        row_ptr, packed, hbf, w2bfT, b2, out, N);
}